// Round 13
// baseline (933.375 us; speedup 1.0000x reference)
//
#include <hip/hip_runtime.h>
#include <hip/hip_bf16.h>

using bf16 = __hip_bfloat16;
typedef __bf16 bf16x8 __attribute__((ext_vector_type(8)));
typedef __bf16 bf16x4v __attribute__((ext_vector_type(4)));
typedef float f32x4 __attribute__((ext_vector_type(4)));

#define MROWS 100352   // 2048 windows * 49 tokens = 32*3136

__device__ __forceinline__ void async16(void* l, const void* g) {
    void* gg = const_cast<void*>(g);
    __builtin_amdgcn_global_load_lds((__attribute__((address_space(1))) void*)gg,
                                     (__attribute__((address_space(3))) void*)l, 16, 0, 0);
}

// tanh-gelu via sigmoid identity: 0.5x(1+tanh(u)) == x*sigmoid(2u).
// 9 VALU ops (the old 2/(e+1) form hid a ~10-instr precise division).
__device__ __forceinline__ float gelu_f(float x) {
    float u = x * fmaf(0.044715f * x, x, 1.0f);          // x + 0.044715x^3
    float e = __expf(-1.5957691216057308f * u);          // exp(-2*0.7978845608*u)
    return x * __builtin_amdgcn_rcpf(1.0f + e);          // x*sigmoid(2u); inf-safe
}

struct Cvt8 { const float* s[8]; bf16* d[8]; int n[8]; };

__global__ __launch_bounds__(256) void cvt8_k(Cvt8 c) {
    int seg = blockIdx.y;
    int i4 = (blockIdx.x * 256 + threadIdx.x) * 4;
    if (i4 < c.n[seg]) {
        float4 v = *(const float4*)(c.s[seg] + i4);
        bf16* d = c.d[seg] + i4;
        d[0] = __float2bfloat16(v.x);
        d[1] = __float2bfloat16(v.y);
        d[2] = __float2bfloat16(v.z);
        d[3] = __float2bfloat16(v.w);
    }
}

// merged proj weight: Wm[384][384] = proj_u(384x192) @ proj_v(192x384), bf16.
// (o@Vp^T)@Up^T == o@(Up Vp)^T -- equal FLOPs at K=384, kills one GEMM+roundtrip.
__global__ __launch_bounds__(384) void wmerge_k(const float* __restrict__ u,
                                                const float* __restrict__ v,
                                                bf16* __restrict__ wm) {
    int o = blockIdx.x, i = threadIdx.x;
    const float* ur = u + o * 192;
    float acc = 0.f;
    for (int r = 0; r < 192; ++r) acc = fmaf(ur[r], v[r * 384 + i], acc);
    wm[o * 384 + i] = __float2bfloat16(acc);
}

// Precompute attn bias (rpb + shift-mask) in C-fragment layout.
__global__ __launch_bounds__(256) void bias_pre_k(const float* __restrict__ rpbt,
                                                  float* __restrict__ biasf) {
    int wt = blockIdx.x / 12, h = blockIdx.x % 12;
    int t = threadIdx.x;
    int lane = t >> 2, tb = t & 3;
    int hi = lane >> 4, lo = lane & 15;
    int m = tb * 16 + lo;
    bool bH = (wt & 2) != 0, bW = (wt & 1) != 0;
    float* outb = biasf + (size_t)blockIdx.x * 4096;
    int mm = m < 49 ? m : 0;
    int i2 = mm / 7, j2 = mm % 7;
    int rm = (bH ? (i2 < 4 ? 1 : 2) : 0) * 3 + (bW ? (j2 < 4 ? 1 : 2) : 0);
#pragma unroll
    for (int ta = 0; ta < 4; ++ta) {
#pragma unroll
        for (int j = 0; j < 4; ++j) {
            int n = ta * 16 + hi * 4 + j;
            float v;
            if (n < 49 && m < 49) {
                int i1 = n / 7, j1 = n % 7;
                int rn = (bH ? (i1 < 4 ? 1 : 2) : 0) * 3 + (bW ? (j1 < 4 ? 1 : 2) : 0);
                v = rpbt[((i1 - i2 + 6) * 13 + (j1 - j2 + 6)) * 12 + h];
                if (rn != rm) v -= 100.0f;
            } else {
                v = -1e30f;
            }
            outb[(ta * 4 + j) * 256 + t] = v;
        }
    }
}

// LN1 + cyclic shift(-3,-3) + window partition. One wave per output row.
__global__ __launch_bounds__(256) void ln1_window_k(const float* __restrict__ x,
                                                    const float* __restrict__ g,
                                                    const float* __restrict__ bta,
                                                    bf16* __restrict__ ywin) {
    int wrow = blockIdx.x * 4 + (threadIdx.x >> 6);
    int lane = threadIdx.x & 63;
    int tok = wrow % 49, win = wrow / 49;
    int i = tok / 7, j = tok % 7;
    int wwi = win & 7, whi = (win >> 3) & 7, bi = win >> 6;
    int hs = (whi * 7 + i + 3) % 56;
    int ws_ = (wwi * 7 + j + 3) % 56;
    const float* xr = x + ((size_t)bi * 3136 + (size_t)hs * 56 + ws_) * 384;
    float v[6]; float s = 0.f, s2 = 0.f;
#pragma unroll
    for (int u = 0; u < 6; ++u) { float t = xr[lane + 64 * u]; v[u] = t; s += t; s2 += t * t; }
#pragma unroll
    for (int d = 1; d < 64; d <<= 1) { s += __shfl_xor(s, d); s2 += __shfl_xor(s2, d); }
    float mean = s * (1.0f / 384.0f);
    float var = s2 * (1.0f / 384.0f) - mean * mean;
    float rstd = rsqrtf(var + 1e-5f);
    bf16* yr = ywin + (size_t)wrow * 384;
#pragma unroll
    for (int u = 0; u < 6; ++u) {
        int c = lane + 64 * u;
        yr[c] = __float2bfloat16((v[u] - mean) * rstd * g[c] + bta[c]);
    }
}

// residual add (window-reverse + roll(+3,+3)) + LN2. x2 -> d_out (fp32), z -> bf16
__global__ __launch_bounds__(256) void resid_ln2_k(const float* __restrict__ x,
                                                   const bf16* __restrict__ proj,
                                                   const float* __restrict__ g,
                                                   const float* __restrict__ bta,
                                                   float* __restrict__ x2,
                                                   bf16* __restrict__ z) {
    int row = blockIdx.x * 4 + (threadIdx.x >> 6);
    int lane = threadIdx.x & 63;
    int bi = row / 3136; int hw = row % 3136;
    int h = hw / 56, w = hw % 56;
    int h2 = (h + 53) % 56, w2 = (w + 53) % 56;
    int prow = ((bi * 8 + h2 / 7) * 8 + w2 / 7) * 49 + (h2 % 7) * 7 + (w2 % 7);
    const float* xr = x + (size_t)row * 384;
    const bf16* pr = proj + (size_t)prow * 384;
    float* x2r = x2 + (size_t)row * 384;
    float v[6]; float s = 0.f, s2 = 0.f;
#pragma unroll
    for (int u = 0; u < 6; ++u) {
        int c = lane + 64 * u;
        float t = xr[c] + __bfloat162float(pr[c]);
        v[u] = t; s += t; s2 += t * t;
        x2r[c] = t;
    }
#pragma unroll
    for (int d = 1; d < 64; d <<= 1) { s += __shfl_xor(s, d); s2 += __shfl_xor(s2, d); }
    float mean = s * (1.0f / 384.0f);
    float var = s2 * (1.0f / 384.0f) - mean * mean;
    float rstd = rsqrtf(var + 1e-5f);
    bf16* zr = z + (size_t)row * 384;
#pragma unroll
    for (int u = 0; u < 6; ++u) {
        int c = lane + 64 * u;
        zr[c] = __float2bfloat16((v[u] - mean) * rstd * g[c] + bta[c]);
    }
}

// MFMA windowed attention: grid (2048 windows, 3 head-groups); 4 waves,
// one wave per head; barrier-free; precomputed fragment-layout bias.
__global__ __launch_bounds__(256) void attn_mfma_k(const bf16* __restrict__ qkv,
                                                   const float* __restrict__ biasf,
                                                   bf16* __restrict__ o) {
    __shared__ __align__(16) __bf16 vt_s[4][32 * 72];   // V^T  [d][m], m padded to 64
    __shared__ __align__(16) __bf16 p_s[4][32 * 72];    // P half [n_loc][m]
    const int win = blockIdx.x;
    const int r = blockIdx.y;
    const int wave = threadIdx.x >> 6, lane = threadIdx.x & 63;
    const int lo = lane & 15, hi = lane >> 4;
    const int whi = (win >> 3) & 7, wwi = win & 7;
    const int wt = ((whi == 7) ? 2 : 0) + ((wwi == 7) ? 1 : 0);
    __bf16* vt_w = vt_s[wave];
    __bf16* p_w = p_s[wave];
    const int h = r * 4 + wave;
    const bf16* qbase = qkv + (size_t)win * 49 * 1152 + h * 32;
    const float* btile = biasf + (size_t)(wt * 12 + h) * 4096;
    bf16x8 zf = {};

    // V -> LDS transposed; lane handles column m
    {
        int m = lane;
        bf16x8 vrow[4];
#pragma unroll
        for (int d8 = 0; d8 < 4; ++d8)
            vrow[d8] = (m < 49) ? *(const bf16x8*)(qbase + (size_t)m * 1152 + 768 + d8 * 8) : zf;
#pragma unroll
        for (int d8 = 0; d8 < 4; ++d8)
#pragma unroll
            for (int e = 0; e < 8; ++e)
                vt_w[(d8 * 8 + e) * 72 + m] = vrow[d8][e];
    }
    bf16x8 aq[4], bk[4];
    const int kq = hi * 8;
#pragma unroll
    for (int ta = 0; ta < 4; ++ta) {
        int n = ta * 16 + lo;
        aq[ta] = (n < 49) ? *(const bf16x8*)(qbase + (size_t)n * 1152 + kq) : zf;
        bk[ta] = (n < 49) ? *(const bf16x8*)(qbase + (size_t)n * 1152 + 384 + kq) : zf;
    }
    f32x4 acc[4][4] = {};
#pragma unroll
    for (int ta = 0; ta < 4; ++ta)
#pragma unroll
        for (int tb = 0; tb < 4; ++tb)
            acc[ta][tb] = __builtin_amdgcn_mfma_f32_16x16x32_bf16(aq[ta], bk[tb], acc[ta][tb], 0, 0, 0);
#pragma unroll
    for (int ta = 0; ta < 4; ++ta) {
#pragma unroll
        for (int j = 0; j < 4; ++j) {
            float4 b4 = *(const float4*)(btile + (ta * 4 + j) * 256 + lane * 4);
            acc[ta][0][j] = fmaf(acc[ta][0][j], 0.17677669529663687f, b4.x);
            acc[ta][1][j] = fmaf(acc[ta][1][j], 0.17677669529663687f, b4.y);
            acc[ta][2][j] = fmaf(acc[ta][2][j], 0.17677669529663687f, b4.z);
            acc[ta][3][j] = fmaf(acc[ta][3][j], 0.17677669529663687f, b4.w);
        }
    }
    bf16x8 vb[2][2];
#pragma unroll
    for (int kb = 0; kb < 2; ++kb)
#pragma unroll
        for (int tb = 0; tb < 2; ++tb)
            vb[kb][tb] = *(const bf16x8*)(vt_w + (tb * 16 + lo) * 72 + kb * 32 + hi * 8);

    f32x4 oacc[4][2] = {};
#pragma unroll
    for (int half = 0; half < 2; ++half) {
#pragma unroll
        for (int tq = 0; tq < 2; ++tq) {
            int ta = half * 2 + tq;
#pragma unroll
            for (int j = 0; j < 4; ++j) {
                float mx = fmaxf(fmaxf(acc[ta][0][j], acc[ta][1][j]),
                                 fmaxf(acc[ta][2][j], acc[ta][3][j]));
                mx = fmaxf(mx, __shfl_xor(mx, 1));
                mx = fmaxf(mx, __shfl_xor(mx, 2));
                mx = fmaxf(mx, __shfl_xor(mx, 4));
                mx = fmaxf(mx, __shfl_xor(mx, 8));
                float e0 = __expf(acc[ta][0][j] - mx);
                float e1 = __expf(acc[ta][1][j] - mx);
                float e2 = __expf(acc[ta][2][j] - mx);
                float e3 = __expf(acc[ta][3][j] - mx);
                float sm = e0 + e1 + e2 + e3;
                sm += __shfl_xor(sm, 1);
                sm += __shfl_xor(sm, 2);
                sm += __shfl_xor(sm, 4);
                sm += __shfl_xor(sm, 8);
                float inv = __builtin_amdgcn_rcpf(sm);
                int nl = tq * 16 + hi * 4 + j;
                p_w[nl * 72 + lo]      = (__bf16)(e0 * inv);
                p_w[nl * 72 + 16 + lo] = (__bf16)(e1 * inv);
                p_w[nl * 72 + 32 + lo] = (__bf16)(e2 * inv);
                p_w[nl * 72 + 48 + lo] = (__bf16)(e3 * inv);
            }
        }
#pragma unroll
        for (int kb = 0; kb < 2; ++kb) {
#pragma unroll
            for (int tq = 0; tq < 2; ++tq) {
                bf16x8 pa = *(const bf16x8*)(p_w + (tq * 16 + lo) * 72 + kb * 32 + hi * 8);
#pragma unroll
                for (int tb = 0; tb < 2; ++tb)
                    oacc[half * 2 + tq][tb] =
                        __builtin_amdgcn_mfma_f32_16x16x32_bf16(pa, vb[kb][tb], oacc[half * 2 + tq][tb], 0, 0, 0);
            }
        }
    }
    bf16* obase = o + (size_t)win * 49 * 384 + h * 32;
#pragma unroll
    for (int ta = 0; ta < 4; ++ta) {
#pragma unroll
        for (int j = 0; j < 4; ++j) {
            int n = ta * 16 + hi * 4 + j;
            if (n < 49) {
#pragma unroll
                for (int tb = 0; tb < 2; ++tb)
                    obase[(size_t)n * 384 + tb * 16 + lo] = __float2bfloat16(oacc[ta][tb][j]);
            }
        }
    }
}

// V-GEMMs (N=192): unchanged 256-thr 128x64 template from round 12.
template <int K, int N, int EPI>
__global__ __launch_bounds__(256, 6) void gemm_bt(const bf16* __restrict__ A,
                                                  const bf16* __restrict__ W,
                                                  const float* __restrict__ bias,
                                                  void* __restrict__ Cout) {
    __shared__ __align__(16) bf16 lds_a[128 * 64];
    __shared__ __align__(16) bf16 lds_b[64 * 64];
    const int t = threadIdx.x;
    const int wave = t >> 6, lane = t & 63;
    const int gdx = gridDim.x;
    int flat = blockIdx.y * gdx + blockIdx.x;
    int q = (gdx * gridDim.y) >> 3;
    int work = (flat & 7) * q + (flat >> 3);
    const int n0 = (work % gdx) * 64, m0 = (work / gdx) * 128;
    const int wm = wave >> 1, wn = wave & 1;
    const int fr = lane & 15, hi = lane >> 4;
    const int srow = t >> 3;
    const int gslot = (t & 7) ^ (srow & 7);
    const bf16* abase = A + (size_t)(m0 + srow) * K + gslot * 8;
    const bf16* bbase = W + (size_t)(n0 + srow) * K + gslot * 8;
    char* la = (char*)lds_a + t * 16;
    char* lb = (char*)lds_b + t * 16;
    const int fp = fr & 7;
    const char* ra0 = (const char*)lds_a + (wm * 64 + fr) * 128 + (hi ^ fp) * 16;
    const char* ra1 = (const char*)lds_a + (wm * 64 + fr) * 128 + ((4 + hi) ^ fp) * 16;
    const char* rb0 = (const char*)lds_b + (wn * 32 + fr) * 128 + (hi ^ fp) * 16;
    const char* rb1 = (const char*)lds_b + (wn * 32 + fr) * 128 + ((4 + hi) ^ fp) * 16;
    f32x4 acc[4][2] = {};
#pragma unroll
    for (int kt = 0; kt < K; kt += 64) {
        if (kt > 0) __syncthreads();
#pragma unroll
        for (int i = 0; i < 4; ++i)
            async16(la + i * 4096, abase + (size_t)i * 32 * K + kt);
#pragma unroll
        for (int i = 0; i < 2; ++i)
            async16(lb + i * 4096, bbase + (size_t)i * 32 * K + kt);
        __syncthreads();
        bf16x8 af[4], bfr[2];
#pragma unroll
        for (int mi = 0; mi < 4; ++mi) af[mi] = *(const bf16x8*)(ra0 + mi * 2048);
#pragma unroll
        for (int ni = 0; ni < 2; ++ni) bfr[ni] = *(const bf16x8*)(rb0 + ni * 2048);
#pragma unroll
        for (int mi = 0; mi < 4; ++mi)
#pragma unroll
            for (int ni = 0; ni < 2; ++ni)
                acc[mi][ni] = __builtin_amdgcn_mfma_f32_16x16x32_bf16(bfr[ni], af[mi], acc[mi][ni], 0, 0, 0);
#pragma unroll
        for (int mi = 0; mi < 4; ++mi) af[mi] = *(const bf16x8*)(ra1 + mi * 2048);
#pragma unroll
        for (int ni = 0; ni < 2; ++ni) bfr[ni] = *(const bf16x8*)(rb1 + ni * 2048);
#pragma unroll
        for (int mi = 0; mi < 4; ++mi)
#pragma unroll
            for (int ni = 0; ni < 2; ++ni)
                acc[mi][ni] = __builtin_amdgcn_mfma_f32_16x16x32_bf16(bfr[ni], af[mi], acc[mi][ni], 0, 0, 0);
    }
    const int rq4 = hi * 4;
    const int ncol = n0 + wn * 32 + rq4;
    const size_t cbase = (size_t)(m0 + wm * 64 + fr) * N + ncol;
    const float* pb = bias ? bias + ncol : nullptr;
#pragma unroll
    for (int mi = 0; mi < 4; ++mi) {
#pragma unroll
        for (int ni = 0; ni < 2; ++ni) {
            float v0 = acc[mi][ni][0], v1 = acc[mi][ni][1];
            float v2 = acc[mi][ni][2], v3 = acc[mi][ni][3];
            if (pb) {
                float4 b4 = *(const float4*)(pb + ni * 16);
                v0 += b4.x; v1 += b4.y; v2 += b4.z; v3 += b4.w;
            }
            if (EPI == 1) { v0 = gelu_f(v0); v1 = gelu_f(v1); v2 = gelu_f(v2); v3 = gelu_f(v3); }
            if (EPI == 2) {
                float4* p = (float4*)((float*)Cout + cbase + (size_t)mi * 16 * N + ni * 16);
                float4 o = *p;
                o.x += v0; o.y += v1; o.z += v2; o.w += v3;
                *p = o;
            } else {
                bf16x4v st = { (__bf16)v0, (__bf16)v1, (__bf16)v2, (__bf16)v3 };
                *(bf16x4v*)((bf16*)Cout + cbase + (size_t)mi * 16 * N + ni * 16) = st;
            }
        }
    }
}

// U-GEMMs + merged proj: 512-thr 128x128 tile, A-only LDS (16 KB);
// B fragments straight from L2 into registers per K-step (W <= 576 KB,
// L2-hot; unroll-1 keeps the 4 loads in-loop so VGPR stays bounded).
template <int K, int N, int EPI>
__global__ __launch_bounds__(512, 6) void gemm_bu(const bf16* __restrict__ A,
                                                  const bf16* __restrict__ W,
                                                  const float* __restrict__ bias,
                                                  void* __restrict__ Cout) {
    __shared__ __align__(16) bf16 lds_a[128 * 64];
    const int t = threadIdx.x;
    const int wave = t >> 6, lane = t & 63;
    const int gdx = gridDim.x;
    int flat = blockIdx.y * gdx + blockIdx.x;
    int q = (gdx * gridDim.y) >> 3;
    int work = (flat & 7) * q + (flat >> 3);
    const int n0 = (work % gdx) * 128, m0 = (work / gdx) * 128;
    const int wm = wave >> 2, wn = wave & 3;
    const int fr = lane & 15, hi = lane >> 4;
    const int srow = t >> 3;                        // 0..63
    const int gslot = (t & 7) ^ (srow & 7);
    const bf16* abase = A + (size_t)(m0 + srow) * K + gslot * 8;
    char* la = (char*)lds_a + t * 16;
    const bf16* wbase = W + (size_t)(n0 + wn * 32 + fr) * K + hi * 8;
    const int fp = fr & 7;
    const char* ra0 = (const char*)lds_a + (wm * 64 + fr) * 128 + (hi ^ fp) * 16;
    const char* ra1 = (const char*)lds_a + (wm * 64 + fr) * 128 + ((4 + hi) ^ fp) * 16;
    f32x4 acc[4][2] = {};
#pragma unroll 1
    for (int kt = 0; kt < K; kt += 64) {
        bf16x8 b00 = *(const bf16x8*)(wbase + kt);
        bf16x8 b01 = *(const bf16x8*)(wbase + (size_t)16 * K + kt);
        bf16x8 b10 = *(const bf16x8*)(wbase + kt + 32);
        bf16x8 b11 = *(const bf16x8*)(wbase + (size_t)16 * K + kt + 32);
        if (kt > 0) __syncthreads();
        async16(la, abase + kt);
        async16(la + 8192, abase + (size_t)64 * K + kt);
        __syncthreads();
        bf16x8 af[4];
#pragma unroll
        for (int mi = 0; mi < 4; ++mi) af[mi] = *(const bf16x8*)(ra0 + mi * 2048);
#pragma unroll
        for (int mi = 0; mi < 4; ++mi) {
            acc[mi][0] = __builtin_amdgcn_mfma_f32_16x16x32_bf16(b00, af[mi], acc[mi][0], 0, 0, 0);
            acc[mi][1] = __builtin_amdgcn_mfma_f32_16x16x32_bf16(b01, af[mi], acc[mi][1], 0, 0, 0);
        }
#pragma unroll
        for (int mi = 0; mi < 4; ++mi) af[mi] = *(const bf16x8*)(ra1 + mi * 2048);
#pragma unroll
        for (int mi = 0; mi < 4; ++mi) {
            acc[mi][0] = __builtin_amdgcn_mfma_f32_16x16x32_bf16(b10, af[mi], acc[mi][0], 0, 0, 0);
            acc[mi][1] = __builtin_amdgcn_mfma_f32_16x16x32_bf16(b11, af[mi], acc[mi][1], 0, 0, 0);
        }
    }
    const int rq4 = hi * 4;
    const int ncol = n0 + wn * 32 + rq4;
    const size_t cbase = (size_t)(m0 + wm * 64 + fr) * N + ncol;
    const float* pb = bias ? bias + ncol : nullptr;
#pragma unroll
    for (int mi = 0; mi < 4; ++mi) {
#pragma unroll
        for (int ni = 0; ni < 2; ++ni) {
            float v0 = acc[mi][ni][0], v1 = acc[mi][ni][1];
            float v2 = acc[mi][ni][2], v3 = acc[mi][ni][3];
            if (pb) {
                float4 b4 = *(const float4*)(pb + ni * 16);
                v0 += b4.x; v1 += b4.y; v2 += b4.z; v3 += b4.w;
            }
            if (EPI == 1) { v0 = gelu_f(v0); v1 = gelu_f(v1); v2 = gelu_f(v2); v3 = gelu_f(v3); }
            if (EPI == 2) {
                float4* p = (float4*)((float*)Cout + cbase + (size_t)mi * 16 * N + ni * 16);
                float4 o = *p;
                o.x += v0; o.y += v1; o.z += v2; o.w += v3;
                *p = o;
            } else {
                bf16x4v st = { (__bf16)v0, (__bf16)v1, (__bf16)v2, (__bf16)v3 };
                *(bf16x4v*)((bf16*)Cout + cbase + (size_t)mi * 16 * N + ni * 16) = st;
            }
        }
    }
}

extern "C" void kernel_launch(void* const* d_in, const int* in_sizes, int n_in,
                              void* d_out, int out_size, void* d_ws, size_t ws_size,
                              hipStream_t stream) {
    const float* x      = (const float*)d_in[0];
    const float* n1g    = (const float*)d_in[1];
    const float* n1b    = (const float*)d_in[2];
    const float* rpbt   = (const float*)d_in[3];
    const float* qkv_v  = (const float*)d_in[4];
    const float* qkv_u  = (const float*)d_in[5];
    const float* qkv_b  = (const float*)d_in[6];
    const float* proj_v = (const float*)d_in[7];
    const float* proj_u = (const float*)d_in[8];
    const float* proj_b = (const float*)d_in[9];
    const float* n2g    = (const float*)d_in[10];
    const float* n2b    = (const float*)d_in[11];
    const float* fc1_v  = (const float*)d_in[12];
    const float* fc1_u  = (const float*)d_in[13];
    const float* fc1_b  = (const float*)d_in[14];
    const float* fc2_v  = (const float*)d_in[15];
    const float* fc2_u  = (const float*)d_in[16];
    const float* fc2_b  = (const float*)d_in[17];

    char* ws = (char*)d_ws;
    bf16* wb = (bf16*)ws;
    bf16* w_qkv_v  = wb;
    bf16* w_qkv_u  = wb + 73728;
    bf16* w_proj_v = wb + 294912;
    bf16* w_proj_u = wb + 368640;
    bf16* w_fc1_v  = wb + 442368;
    bf16* w_fc1_u  = wb + 516096;
    bf16* w_fc2_v  = wb + 811008;
    bf16* w_fc2_u  = wb + 1105920;
    bf16* w_proj_m = wb + 1179648;             // 384x384 merged proj (288 KB)
    float* biasf   = (float*)(ws + 3145728);   // 768 KB, ends < 4 MB
    size_t off = (size_t)4 << 20;
    bf16* R1 = (bf16*)(ws + off); off += (size_t)MROWS * 1536 * 2;   // qkv / proj / mlp-hidden
    bf16* R2 = (bf16*)(ws + off); off += (size_t)MROWS * 384 * 2;    // ywin / o / z
    bf16* R3 = (bf16*)(ws + off);                                    // rank-192 temps
    float* out = (float*)d_out;

    Cvt8 c;
    c.s[0] = qkv_v;  c.d[0] = w_qkv_v;  c.n[0] = 73728;
    c.s[1] = qkv_u;  c.d[1] = w_qkv_u;  c.n[1] = 221184;
    c.s[2] = proj_v; c.d[2] = w_proj_v; c.n[2] = 73728;
    c.s[3] = proj_u; c.d[3] = w_proj_u; c.n[3] = 73728;
    c.s[4] = fc1_v;  c.d[4] = w_fc1_v;  c.n[4] = 73728;
    c.s[5] = fc1_u;  c.d[5] = w_fc1_u;  c.n[5] = 294912;
    c.s[6] = fc2_v;  c.d[6] = w_fc2_v;  c.n[6] = 294912;
    c.s[7] = fc2_u;  c.d[7] = w_fc2_u;  c.n[7] = 73728;
    cvt8_k<<<dim3(288, 8), 256, 0, stream>>>(c);
    bias_pre_k<<<48, 256, 0, stream>>>(rpbt, biasf);
    wmerge_k<<<384, 384, 0, stream>>>(proj_u, proj_v, w_proj_m);

    ln1_window_k<<<MROWS / 4, 256, 0, stream>>>(x, n1g, n1b, R2);
    gemm_bt<384, 192, 0><<<dim3(3, 784), 256, 0, stream>>>(R2, w_qkv_v, nullptr, R3);
    gemm_bu<192, 1152, 0><<<dim3(9, 784), 512, 0, stream>>>(R3, w_qkv_u, qkv_b, R1);
    attn_mfma_k<<<dim3(2048, 3), 256, 0, stream>>>(R1, biasf, R2);
    gemm_bu<384, 384, 0><<<dim3(3, 784), 512, 0, stream>>>(R2, w_proj_m, proj_b, R1);
    resid_ln2_k<<<MROWS / 4, 256, 0, stream>>>(x, R1, n2g, n2b, out, R2);
    gemm_bt<384, 192, 0><<<dim3(3, 784), 256, 0, stream>>>(R2, w_fc1_v, nullptr, R3);
    gemm_bu<192, 1536, 1><<<dim3(12, 784), 512, 0, stream>>>(R3, w_fc1_u, fc1_b, R1);
    gemm_bt<1536, 192, 0><<<dim3(3, 784), 256, 0, stream>>>(R1, w_fc2_v, nullptr, R3);
    gemm_bu<192, 384, 2><<<dim3(3, 784), 512, 0, stream>>>(R3, w_fc2_u, fc2_b, out);
}

// Round 14
// 863.725 us; speedup vs baseline: 1.0806x; 1.0806x over previous
//
#include <hip/hip_runtime.h>
#include <hip/hip_bf16.h>

using bf16 = __hip_bfloat16;
typedef __bf16 bf16x8 __attribute__((ext_vector_type(8)));
typedef __bf16 bf16x4v __attribute__((ext_vector_type(4)));
typedef float f32x4 __attribute__((ext_vector_type(4)));

#define MROWS 100352   // 2048 windows * 49 tokens = 32*3136

__device__ __forceinline__ void async16(void* l, const void* g) {
    void* gg = const_cast<void*>(g);
    __builtin_amdgcn_global_load_lds((__attribute__((address_space(1))) void*)gg,
                                     (__attribute__((address_space(3))) void*)l, 16, 0, 0);
}

// tanh-gelu via sigmoid identity: 0.5x(1+tanh(u)) == x*sigmoid(2u)
__device__ __forceinline__ float gelu_f(float x) {
    float u = x * fmaf(0.044715f * x, x, 1.0f);
    float e = __expf(-1.5957691216057308f * u);
    return x * __builtin_amdgcn_rcpf(1.0f + e);
}

struct Cvt8 { const float* s[8]; bf16* d[8]; int n[8]; };

__global__ __launch_bounds__(256) void cvt8_k(Cvt8 c) {
    int seg = blockIdx.y;
    int i4 = (blockIdx.x * 256 + threadIdx.x) * 4;
    if (i4 < c.n[seg]) {
        float4 v = *(const float4*)(c.s[seg] + i4);
        bf16* d = c.d[seg] + i4;
        d[0] = __float2bfloat16(v.x);
        d[1] = __float2bfloat16(v.y);
        d[2] = __float2bfloat16(v.z);
        d[3] = __float2bfloat16(v.w);
    }
}

// merged proj weight: Wm[384][384] = proj_u(384x192) @ proj_v(192x384), bf16.
__global__ __launch_bounds__(384) void wmerge_k(const float* __restrict__ u,
                                                const float* __restrict__ v,
                                                bf16* __restrict__ wm) {
    int o = blockIdx.x, i = threadIdx.x;
    const float* ur = u + o * 192;
    float acc = 0.f;
    for (int r = 0; r < 192; ++r) acc = fmaf(ur[r], v[r * 384 + i], acc);
    wm[o * 384 + i] = __float2bfloat16(acc);
}

// Precompute attn bias (rpb + shift-mask) in C-fragment layout.
__global__ __launch_bounds__(256) void bias_pre_k(const float* __restrict__ rpbt,
                                                  float* __restrict__ biasf) {
    int wt = blockIdx.x / 12, h = blockIdx.x % 12;
    int t = threadIdx.x;
    int lane = t >> 2, tb = t & 3;
    int hi = lane >> 4, lo = lane & 15;
    int m = tb * 16 + lo;
    bool bH = (wt & 2) != 0, bW = (wt & 1) != 0;
    float* outb = biasf + (size_t)blockIdx.x * 4096;
    int mm = m < 49 ? m : 0;
    int i2 = mm / 7, j2 = mm % 7;
    int rm = (bH ? (i2 < 4 ? 1 : 2) : 0) * 3 + (bW ? (j2 < 4 ? 1 : 2) : 0);
#pragma unroll
    for (int ta = 0; ta < 4; ++ta) {
#pragma unroll
        for (int j = 0; j < 4; ++j) {
            int n = ta * 16 + hi * 4 + j;
            float v;
            if (n < 49 && m < 49) {
                int i1 = n / 7, j1 = n % 7;
                int rn = (bH ? (i1 < 4 ? 1 : 2) : 0) * 3 + (bW ? (j1 < 4 ? 1 : 2) : 0);
                v = rpbt[((i1 - i2 + 6) * 13 + (j1 - j2 + 6)) * 12 + h];
                if (rn != rm) v -= 100.0f;
            } else {
                v = -1e30f;
            }
            outb[(ta * 4 + j) * 256 + t] = v;
        }
    }
}

// LN1 + cyclic shift(-3,-3) + window partition. One wave per output row.
__global__ __launch_bounds__(256) void ln1_window_k(const float* __restrict__ x,
                                                    const float* __restrict__ g,
                                                    const float* __restrict__ bta,
                                                    bf16* __restrict__ ywin) {
    int wrow = blockIdx.x * 4 + (threadIdx.x >> 6);
    int lane = threadIdx.x & 63;
    int tok = wrow % 49, win = wrow / 49;
    int i = tok / 7, j = tok % 7;
    int wwi = win & 7, whi = (win >> 3) & 7, bi = win >> 6;
    int hs = (whi * 7 + i + 3) % 56;
    int ws_ = (wwi * 7 + j + 3) % 56;
    const float* xr = x + ((size_t)bi * 3136 + (size_t)hs * 56 + ws_) * 384;
    float v[6]; float s = 0.f, s2 = 0.f;
#pragma unroll
    for (int u = 0; u < 6; ++u) { float t = xr[lane + 64 * u]; v[u] = t; s += t; s2 += t * t; }
#pragma unroll
    for (int d = 1; d < 64; d <<= 1) { s += __shfl_xor(s, d); s2 += __shfl_xor(s2, d); }
    float mean = s * (1.0f / 384.0f);
    float var = s2 * (1.0f / 384.0f) - mean * mean;
    float rstd = rsqrtf(var + 1e-5f);
    bf16* yr = ywin + (size_t)wrow * 384;
#pragma unroll
    for (int u = 0; u < 6; ++u) {
        int c = lane + 64 * u;
        yr[c] = __float2bfloat16((v[u] - mean) * rstd * g[c] + bta[c]);
    }
}

// residual add (window-reverse + roll(+3,+3)) + LN2. x2 -> d_out (fp32), z -> bf16
__global__ __launch_bounds__(256) void resid_ln2_k(const float* __restrict__ x,
                                                   const bf16* __restrict__ proj,
                                                   const float* __restrict__ g,
                                                   const float* __restrict__ bta,
                                                   float* __restrict__ x2,
                                                   bf16* __restrict__ z) {
    int row = blockIdx.x * 4 + (threadIdx.x >> 6);
    int lane = threadIdx.x & 63;
    int bi = row / 3136; int hw = row % 3136;
    int h = hw / 56, w = hw % 56;
    int h2 = (h + 53) % 56, w2 = (w + 53) % 56;
    int prow = ((bi * 8 + h2 / 7) * 8 + w2 / 7) * 49 + (h2 % 7) * 7 + (w2 % 7);
    const float* xr = x + (size_t)row * 384;
    const bf16* pr = proj + (size_t)prow * 384;
    float* x2r = x2 + (size_t)row * 384;
    float v[6]; float s = 0.f, s2 = 0.f;
#pragma unroll
    for (int u = 0; u < 6; ++u) {
        int c = lane + 64 * u;
        float t = xr[c] + __bfloat162float(pr[c]);
        v[u] = t; s += t; s2 += t * t;
        x2r[c] = t;
    }
#pragma unroll
    for (int d = 1; d < 64; d <<= 1) { s += __shfl_xor(s, d); s2 += __shfl_xor(s2, d); }
    float mean = s * (1.0f / 384.0f);
    float var = s2 * (1.0f / 384.0f) - mean * mean;
    float rstd = rsqrtf(var + 1e-5f);
    bf16* zr = z + (size_t)row * 384;
#pragma unroll
    for (int u = 0; u < 6; ++u) {
        int c = lane + 64 * u;
        zr[c] = __float2bfloat16((v[u] - mean) * rstd * g[c] + bta[c]);
    }
}

// MFMA windowed attention (unchanged, round-10-verified).
__global__ __launch_bounds__(256) void attn_mfma_k(const bf16* __restrict__ qkv,
                                                   const float* __restrict__ biasf,
                                                   bf16* __restrict__ o) {
    __shared__ __align__(16) __bf16 vt_s[4][32 * 72];
    __shared__ __align__(16) __bf16 p_s[4][32 * 72];
    const int win = blockIdx.x;
    const int r = blockIdx.y;
    const int wave = threadIdx.x >> 6, lane = threadIdx.x & 63;
    const int lo = lane & 15, hi = lane >> 4;
    const int whi = (win >> 3) & 7, wwi = win & 7;
    const int wt = ((whi == 7) ? 2 : 0) + ((wwi == 7) ? 1 : 0);
    __bf16* vt_w = vt_s[wave];
    __bf16* p_w = p_s[wave];
    const int h = r * 4 + wave;
    const bf16* qbase = qkv + (size_t)win * 49 * 1152 + h * 32;
    const float* btile = biasf + (size_t)(wt * 12 + h) * 4096;
    bf16x8 zf = {};

    {
        int m = lane;
        bf16x8 vrow[4];
#pragma unroll
        for (int d8 = 0; d8 < 4; ++d8)
            vrow[d8] = (m < 49) ? *(const bf16x8*)(qbase + (size_t)m * 1152 + 768 + d8 * 8) : zf;
#pragma unroll
        for (int d8 = 0; d8 < 4; ++d8)
#pragma unroll
            for (int e = 0; e < 8; ++e)
                vt_w[(d8 * 8 + e) * 72 + m] = vrow[d8][e];
    }
    bf16x8 aq[4], bk[4];
    const int kq = hi * 8;
#pragma unroll
    for (int ta = 0; ta < 4; ++ta) {
        int n = ta * 16 + lo;
        aq[ta] = (n < 49) ? *(const bf16x8*)(qbase + (size_t)n * 1152 + kq) : zf;
        bk[ta] = (n < 49) ? *(const bf16x8*)(qbase + (size_t)n * 1152 + 384 + kq) : zf;
    }
    f32x4 acc[4][4] = {};
#pragma unroll
    for (int ta = 0; ta < 4; ++ta)
#pragma unroll
        for (int tb = 0; tb < 4; ++tb)
            acc[ta][tb] = __builtin_amdgcn_mfma_f32_16x16x32_bf16(aq[ta], bk[tb], acc[ta][tb], 0, 0, 0);
#pragma unroll
    for (int ta = 0; ta < 4; ++ta) {
#pragma unroll
        for (int j = 0; j < 4; ++j) {
            float4 b4 = *(const float4*)(btile + (ta * 4 + j) * 256 + lane * 4);
            acc[ta][0][j] = fmaf(acc[ta][0][j], 0.17677669529663687f, b4.x);
            acc[ta][1][j] = fmaf(acc[ta][1][j], 0.17677669529663687f, b4.y);
            acc[ta][2][j] = fmaf(acc[ta][2][j], 0.17677669529663687f, b4.z);
            acc[ta][3][j] = fmaf(acc[ta][3][j], 0.17677669529663687f, b4.w);
        }
    }
    bf16x8 vb[2][2];
#pragma unroll
    for (int kb = 0; kb < 2; ++kb)
#pragma unroll
        for (int tb = 0; tb < 2; ++tb)
            vb[kb][tb] = *(const bf16x8*)(vt_w + (tb * 16 + lo) * 72 + kb * 32 + hi * 8);

    f32x4 oacc[4][2] = {};
#pragma unroll
    for (int half = 0; half < 2; ++half) {
#pragma unroll
        for (int tq = 0; tq < 2; ++tq) {
            int ta = half * 2 + tq;
#pragma unroll
            for (int j = 0; j < 4; ++j) {
                float mx = fmaxf(fmaxf(acc[ta][0][j], acc[ta][1][j]),
                                 fmaxf(acc[ta][2][j], acc[ta][3][j]));
                mx = fmaxf(mx, __shfl_xor(mx, 1));
                mx = fmaxf(mx, __shfl_xor(mx, 2));
                mx = fmaxf(mx, __shfl_xor(mx, 4));
                mx = fmaxf(mx, __shfl_xor(mx, 8));
                float e0 = __expf(acc[ta][0][j] - mx);
                float e1 = __expf(acc[ta][1][j] - mx);
                float e2 = __expf(acc[ta][2][j] - mx);
                float e3 = __expf(acc[ta][3][j] - mx);
                float sm = e0 + e1 + e2 + e3;
                sm += __shfl_xor(sm, 1);
                sm += __shfl_xor(sm, 2);
                sm += __shfl_xor(sm, 4);
                sm += __shfl_xor(sm, 8);
                float inv = __builtin_amdgcn_rcpf(sm);
                int nl = tq * 16 + hi * 4 + j;
                p_w[nl * 72 + lo]      = (__bf16)(e0 * inv);
                p_w[nl * 72 + 16 + lo] = (__bf16)(e1 * inv);
                p_w[nl * 72 + 32 + lo] = (__bf16)(e2 * inv);
                p_w[nl * 72 + 48 + lo] = (__bf16)(e3 * inv);
            }
        }
#pragma unroll
        for (int kb = 0; kb < 2; ++kb) {
#pragma unroll
            for (int tq = 0; tq < 2; ++tq) {
                bf16x8 pa = *(const bf16x8*)(p_w + (tq * 16 + lo) * 72 + kb * 32 + hi * 8);
#pragma unroll
                for (int tb = 0; tb < 2; ++tb)
                    oacc[half * 2 + tq][tb] =
                        __builtin_amdgcn_mfma_f32_16x16x32_bf16(pa, vb[kb][tb], oacc[half * 2 + tq][tb], 0, 0, 0);
            }
        }
    }
    bf16* obase = o + (size_t)win * 49 * 384 + h * 32;
#pragma unroll
    for (int ta = 0; ta < 4; ++ta) {
#pragma unroll
        for (int j = 0; j < 4; ++j) {
            int n = ta * 16 + hi * 4 + j;
            if (n < 49) {
#pragma unroll
                for (int tb = 0; tb < 2; ++tb)
                    obase[(size_t)n * 384 + tb * 16 + lo] = __float2bfloat16(oacc[ta][tb][j]);
            }
        }
    }
}

// R12-proven GEMM template. WN=2: 256thr 128x64; WN=4: 512thr 128x128.
template <int K, int N, int WN, int EPI>
__global__ __launch_bounds__(WN * 128, 8 - WN) void gemm_bt(const bf16* __restrict__ A,
                                                            const bf16* __restrict__ W,
                                                            const float* __restrict__ bias,
                                                            void* __restrict__ Cout) {
    constexpr int T = WN * 128;
    constexpr int BN = WN * 32;
    __shared__ __align__(16) bf16 lds_a[128 * 64];
    __shared__ __align__(16) bf16 lds_b[BN * 64];
    const int t = threadIdx.x;
    const int wave = t >> 6, lane = t & 63;
    const int gdx = gridDim.x;
    int flat = blockIdx.y * gdx + blockIdx.x;
    int q = (gdx * gridDim.y) >> 3;
    int work = (flat & 7) * q + (flat >> 3);
    const int n0 = (work % gdx) * BN, m0 = (work / gdx) * 128;
    const int wm = wave / WN, wn = wave % WN;
    const int fr = lane & 15, hi = lane >> 4;
    const int srow = t >> 3;
    const int gslot = (t & 7) ^ (srow & 7);
    const bf16* abase = A + (size_t)(m0 + srow) * K + gslot * 8;
    const bf16* bbase = W + (size_t)(n0 + srow) * K + gslot * 8;
    char* la = (char*)lds_a + t * 16;
    char* lb = (char*)lds_b + t * 16;
    const int fp = fr & 7;
    const char* ra0 = (const char*)lds_a + (wm * 64 + fr) * 128 + (hi ^ fp) * 16;
    const char* ra1 = (const char*)lds_a + (wm * 64 + fr) * 128 + ((4 + hi) ^ fp) * 16;
    const char* rb0 = (const char*)lds_b + (wn * 32 + fr) * 128 + (hi ^ fp) * 16;
    const char* rb1 = (const char*)lds_b + (wn * 32 + fr) * 128 + ((4 + hi) ^ fp) * 16;
    f32x4 acc[4][2] = {};
#pragma unroll
    for (int kt = 0; kt < K; kt += 64) {
        if (kt > 0) __syncthreads();
#pragma unroll
        for (int i = 0; i < 1024 / T; ++i)
            async16(la + i * T * 16, abase + (size_t)i * (T >> 3) * K + kt);
#pragma unroll
        for (int i = 0; i < BN * 8 / T; ++i)
            async16(lb + i * T * 16, bbase + (size_t)i * (T >> 3) * K + kt);
        __syncthreads();
        bf16x8 af[4], bfr[2];
#pragma unroll
        for (int mi = 0; mi < 4; ++mi) af[mi] = *(const bf16x8*)(ra0 + mi * 2048);
#pragma unroll
        for (int ni = 0; ni < 2; ++ni) bfr[ni] = *(const bf16x8*)(rb0 + ni * 2048);
#pragma unroll
        for (int mi = 0; mi < 4; ++mi)
#pragma unroll
            for (int ni = 0; ni < 2; ++ni)
                acc[mi][ni] = __builtin_amdgcn_mfma_f32_16x16x32_bf16(bfr[ni], af[mi], acc[mi][ni], 0, 0, 0);
#pragma unroll
        for (int mi = 0; mi < 4; ++mi) af[mi] = *(const bf16x8*)(ra1 + mi * 2048);
#pragma unroll
        for (int ni = 0; ni < 2; ++ni) bfr[ni] = *(const bf16x8*)(rb1 + ni * 2048);
#pragma unroll
        for (int mi = 0; mi < 4; ++mi)
#pragma unroll
            for (int ni = 0; ni < 2; ++ni)
                acc[mi][ni] = __builtin_amdgcn_mfma_f32_16x16x32_bf16(bfr[ni], af[mi], acc[mi][ni], 0, 0, 0);
    }
    const int rq4 = hi * 4;
    const int ncol = n0 + wn * 32 + rq4;
    const size_t cbase = (size_t)(m0 + wm * 64 + fr) * N + ncol;
    const float* pb = bias ? bias + ncol : nullptr;
#pragma unroll
    for (int mi = 0; mi < 4; ++mi) {
#pragma unroll
        for (int ni = 0; ni < 2; ++ni) {
            float v0 = acc[mi][ni][0], v1 = acc[mi][ni][1];
            float v2 = acc[mi][ni][2], v3 = acc[mi][ni][3];
            if (pb) {
                float4 b4 = *(const float4*)(pb + ni * 16);
                v0 += b4.x; v1 += b4.y; v2 += b4.z; v3 += b4.w;
            }
            if (EPI == 1) { v0 = gelu_f(v0); v1 = gelu_f(v1); v2 = gelu_f(v2); v3 = gelu_f(v3); }
            if (EPI == 2) {
                float4* p = (float4*)((float*)Cout + cbase + (size_t)mi * 16 * N + ni * 16);
                float4 o = *p;
                o.x += v0; o.y += v1; o.z += v2; o.w += v3;
                *p = o;
            } else {
                bf16x4v st = { (__bf16)v0, (__bf16)v1, (__bf16)v2, (__bf16)v3 };
                *(bf16x4v*)((bf16*)Cout + cbase + (size_t)mi * 16 * N + ni * 16) = st;
            }
        }
    }
}

// Fused MLP middle: C[M,192] = gelu(A[M,192] @ U^T + b1) @ V2^T.
// Kills the 616 MB hidden-tensor HBM round-trip. Per 128-row block:
// A staged once (48 KB, 24-slot XOR layout); 12 chunks of 128 hidden:
// GEMM1 (U frags from L2) -> gelu -> H in swizzled 32 KB LDS -> GEMM2
// (V2 frags from L2) accumulating C. U=fc1_u[1536][192], V2=fc2_v[192][1536]
// are both B^T-layout and L2-resident (~590 KB each).
__global__ __launch_bounds__(512, 4) void mlp_mid_k(const bf16* __restrict__ A,
                                                    const bf16* __restrict__ U,
                                                    const bf16* __restrict__ V2,
                                                    const float* __restrict__ b1,
                                                    bf16* __restrict__ Cout) {
    __shared__ __align__(16) bf16 lds_a[128 * 192];   // 48 KB
    __shared__ __align__(16) bf16 lds_h[128 * 128];   // 32 KB
    const int t = threadIdx.x;
    const int wave = t >> 6, lane = t & 63;
    const int wm = wave >> 2, wn = wave & 3;
    const int fr = lane & 15, hi = lane >> 4;
    const int fp = fr & 7;
    const int m0 = blockIdx.x * 128;
    // stage A[128][192]: 3072 16B units, 6 per thread
#pragma unroll
    for (int i = 0; i < 6; ++i) {
        int u = i * 512 + t;
        int row = u / 24, slot = u % 24;
        int gslot = slot ^ (row & 7);
        async16((char*)lds_a + u * 16, A + (size_t)(m0 + row) * 192 + gslot * 8);
    }
    __syncthreads();

    f32x4 acc2[4][3] = {};
    const int rowm = wm * 64;                 // wave's m-rows: rowm..rowm+63
    const bf16* ub = U + (size_t)(wn * 32 + fr) * 192 + hi * 8;
    const bf16* vb = V2 + (size_t)(wn * 48 + fr) * 1536 + hi * 8;

    for (int hc = 0; hc < 12; ++hc) {
        // ---- GEMM1: H_wave[64 x 32] over K=192 ----
        f32x4 acc1[4][2] = {};
#pragma unroll
        for (int kk = 0; kk < 6; ++kk) {
            bf16x8 af[4], bu[2];
#pragma unroll
            for (int mi = 0; mi < 4; ++mi) {
                int row = rowm + mi * 16 + fr;
                af[mi] = *(const bf16x8*)((const char*)lds_a + row * 384 + ((kk * 4 + hi) ^ fp) * 16);
            }
#pragma unroll
            for (int nn = 0; nn < 2; ++nn)
                bu[nn] = *(const bf16x8*)(ub + (size_t)(hc * 128 + nn * 16) * 192 + kk * 32);
#pragma unroll
            for (int mi = 0; mi < 4; ++mi)
#pragma unroll
                for (int nn = 0; nn < 2; ++nn)
                    acc1[mi][nn] = __builtin_amdgcn_mfma_f32_16x16x32_bf16(bu[nn], af[mi], acc1[mi][nn], 0, 0, 0);
        }
        if (hc > 0) __syncthreads();   // previous chunk's H reads complete
        // ---- gelu + bias -> H LDS (swizzled: byte ^= (m&7)<<4 within row) ----
#pragma unroll
        for (int nn = 0; nn < 2; ++nn) {
            float4 b4 = *(const float4*)(b1 + hc * 128 + wn * 32 + nn * 16 + hi * 4);
#pragma unroll
            for (int mi = 0; mi < 4; ++mi) {
                int mrow = rowm + mi * 16 + fr;
                float v0 = gelu_f(acc1[mi][nn][0] + b4.x);
                float v1 = gelu_f(acc1[mi][nn][1] + b4.y);
                float v2 = gelu_f(acc1[mi][nn][2] + b4.z);
                float v3 = gelu_f(acc1[mi][nn][3] + b4.w);
                bf16x4v st = { (__bf16)v0, (__bf16)v1, (__bf16)v2, (__bf16)v3 };
                int hb = (wn * 64 + nn * 32 + hi * 8) ^ ((mrow & 7) << 4);
                *(bf16x4v*)((char*)lds_h + mrow * 256 + hb) = st;
            }
        }
        __syncthreads();
        // ---- GEMM2: C[64 x 48] += H[64 x 128] @ V2chunk^T ----
#pragma unroll
        for (int kk = 0; kk < 4; ++kk) {
            bf16x8 af2[4], bv[3];
#pragma unroll
            for (int mi = 0; mi < 4; ++mi) {
                int mrow = rowm + mi * 16 + fr;
                int kb = (kk * 64 + hi * 16) ^ ((mrow & 7) << 4);
                af2[mi] = *(const bf16x8*)((const char*)lds_h + mrow * 256 + kb);
            }
#pragma unroll
            for (int tn = 0; tn < 3; ++tn)
                bv[tn] = *(const bf16x8*)(vb + (size_t)(tn * 16) * 1536 + hc * 128 + kk * 32);
#pragma unroll
            for (int mi = 0; mi < 4; ++mi)
#pragma unroll
                for (int tn = 0; tn < 3; ++tn)
                    acc2[mi][tn] = __builtin_amdgcn_mfma_f32_16x16x32_bf16(bv[tn], af2[mi], acc2[mi][tn], 0, 0, 0);
        }
    }
    // ---- epilogue: C[m][n], n = wn*48 + tn*16 + hi*4 ----
    const size_t cbase = (size_t)(m0 + rowm + fr) * 192 + wn * 48 + hi * 4;
#pragma unroll
    for (int mi = 0; mi < 4; ++mi) {
#pragma unroll
        for (int tn = 0; tn < 3; ++tn) {
            bf16x4v st = { (__bf16)acc2[mi][tn][0], (__bf16)acc2[mi][tn][1],
                           (__bf16)acc2[mi][tn][2], (__bf16)acc2[mi][tn][3] };
            *(bf16x4v*)(Cout + cbase + (size_t)mi * 16 * 192 + tn * 16) = st;
        }
    }
}

extern "C" void kernel_launch(void* const* d_in, const int* in_sizes, int n_in,
                              void* d_out, int out_size, void* d_ws, size_t ws_size,
                              hipStream_t stream) {
    const float* x      = (const float*)d_in[0];
    const float* n1g    = (const float*)d_in[1];
    const float* n1b    = (const float*)d_in[2];
    const float* rpbt   = (const float*)d_in[3];
    const float* qkv_v  = (const float*)d_in[4];
    const float* qkv_u  = (const float*)d_in[5];
    const float* qkv_b  = (const float*)d_in[6];
    const float* proj_v = (const float*)d_in[7];
    const float* proj_u = (const float*)d_in[8];
    const float* proj_b = (const float*)d_in[9];
    const float* n2g    = (const float*)d_in[10];
    const float* n2b    = (const float*)d_in[11];
    const float* fc1_v  = (const float*)d_in[12];
    const float* fc1_u  = (const float*)d_in[13];
    const float* fc1_b  = (const float*)d_in[14];
    const float* fc2_v  = (const float*)d_in[15];
    const float* fc2_u  = (const float*)d_in[16];
    const float* fc2_b  = (const float*)d_in[17];

    char* ws = (char*)d_ws;
    bf16* wb = (bf16*)ws;
    bf16* w_qkv_v  = wb;
    bf16* w_qkv_u  = wb + 73728;
    bf16* w_proj_v = wb + 294912;
    bf16* w_proj_u = wb + 368640;
    bf16* w_fc1_v  = wb + 442368;
    bf16* w_fc1_u  = wb + 516096;
    bf16* w_fc2_v  = wb + 811008;
    bf16* w_fc2_u  = wb + 1105920;
    bf16* w_proj_m = wb + 1179648;             // 384x384 merged proj
    float* biasf   = (float*)(ws + 3145728);   // 768 KB
    size_t off = (size_t)4 << 20;
    bf16* R1 = (bf16*)(ws + off); off += (size_t)MROWS * 1536 * 2;   // qkv / proj-out / mlp-out
    bf16* R2 = (bf16*)(ws + off); off += (size_t)MROWS * 384 * 2;    // ywin / o / z
    bf16* R3 = (bf16*)(ws + off);                                    // rank-192 temps
    float* out = (float*)d_out;

    Cvt8 c;
    c.s[0] = qkv_v;  c.d[0] = w_qkv_v;  c.n[0] = 73728;
    c.s[1] = qkv_u;  c.d[1] = w_qkv_u;  c.n[1] = 221184;
    c.s[2] = proj_v; c.d[2] = w_proj_v; c.n[2] = 73728;
    c.s[3] = proj_u; c.d[3] = w_proj_u; c.n[3] = 73728;
    c.s[4] = fc1_v;  c.d[4] = w_fc1_v;  c.n[4] = 73728;
    c.s[5] = fc1_u;  c.d[5] = w_fc1_u;  c.n[5] = 294912;
    c.s[6] = fc2_v;  c.d[6] = w_fc2_v;  c.n[6] = 294912;
    c.s[7] = fc2_u;  c.d[7] = w_fc2_u;  c.n[7] = 73728;
    cvt8_k<<<dim3(288, 8), 256, 0, stream>>>(c);
    bias_pre_k<<<48, 256, 0, stream>>>(rpbt, biasf);
    wmerge_k<<<384, 384, 0, stream>>>(proj_u, proj_v, w_proj_m);

    ln1_window_k<<<MROWS / 4, 256, 0, stream>>>(x, n1g, n1b, R2);
    gemm_bt<384, 192, 2, 0><<<dim3(3, 784), 256, 0, stream>>>(R2, w_qkv_v, nullptr, R3);
    gemm_bt<192, 1152, 4, 0><<<dim3(9, 784), 512, 0, stream>>>(R3, w_qkv_u, qkv_b, R1);
    attn_mfma_k<<<dim3(2048, 3), 256, 0, stream>>>(R1, biasf, R2);
    gemm_bt<384, 384, 4, 0><<<dim3(3, 784), 512, 0, stream>>>(R2, w_proj_m, proj_b, R1);
    resid_ln2_k<<<MROWS / 4, 256, 0, stream>>>(x, R1, n2g, n2b, out, R2);
    gemm_bt<384, 192, 2, 0><<<dim3(3, 784), 256, 0, stream>>>(R2, w_fc1_v, nullptr, R3);
    mlp_mid_k<<<784, 512, 0, stream>>>(R3, w_fc1_u, w_fc2_v, fc1_b, R1);
    gemm_bt<192, 384, 4, 2><<<dim3(3, 784), 512, 0, stream>>>(R1, w_fc2_u, fc2_b, out);
}

// Round 15
// 810.706 us; speedup vs baseline: 1.1513x; 1.0654x over previous
//
#include <hip/hip_runtime.h>
#include <hip/hip_bf16.h>

using bf16 = __hip_bfloat16;
typedef __bf16 bf16x8 __attribute__((ext_vector_type(8)));
typedef __bf16 bf16x4v __attribute__((ext_vector_type(4)));
typedef float f32x4 __attribute__((ext_vector_type(4)));

#define MROWS 100352   // 2048 windows * 49 tokens = 32*3136

__device__ __forceinline__ void async16(void* l, const void* g) {
    void* gg = const_cast<void*>(g);
    __builtin_amdgcn_global_load_lds((__attribute__((address_space(1))) void*)gg,
                                     (__attribute__((address_space(3))) void*)l, 16, 0, 0);
}

// tanh-gelu via sigmoid identity: 0.5x(1+tanh(u)) == x*sigmoid(2u)
__device__ __forceinline__ float gelu_f(float x) {
    float u = x * fmaf(0.044715f * x, x, 1.0f);
    float e = __expf(-1.5957691216057308f * u);
    return x * __builtin_amdgcn_rcpf(1.0f + e);
}

struct Cvt8 { const float* s[8]; bf16* d[8]; int n[8]; };

__global__ __launch_bounds__(256) void cvt8_k(Cvt8 c) {
    int seg = blockIdx.y;
    int i4 = (blockIdx.x * 256 + threadIdx.x) * 4;
    if (i4 < c.n[seg]) {
        float4 v = *(const float4*)(c.s[seg] + i4);
        bf16* d = c.d[seg] + i4;
        d[0] = __float2bfloat16(v.x);
        d[1] = __float2bfloat16(v.y);
        d[2] = __float2bfloat16(v.z);
        d[3] = __float2bfloat16(v.w);
    }
}

// merged proj weight: Wm[384][384] = proj_u(384x192) @ proj_v(192x384), bf16.
__global__ __launch_bounds__(384) void wmerge_k(const float* __restrict__ u,
                                                const float* __restrict__ v,
                                                bf16* __restrict__ wm) {
    int o = blockIdx.x, i = threadIdx.x;
    const float* ur = u + o * 192;
    float acc = 0.f;
    for (int r = 0; r < 192; ++r) acc = fmaf(ur[r], v[r * 384 + i], acc);
    wm[o * 384 + i] = __float2bfloat16(acc);
}

// Precompute attn bias (rpb + shift-mask) in C-fragment layout.
__global__ __launch_bounds__(256) void bias_pre_k(const float* __restrict__ rpbt,
                                                  float* __restrict__ biasf) {
    int wt = blockIdx.x / 12, h = blockIdx.x % 12;
    int t = threadIdx.x;
    int lane = t >> 2, tb = t & 3;
    int hi = lane >> 4, lo = lane & 15;
    int m = tb * 16 + lo;
    bool bH = (wt & 2) != 0, bW = (wt & 1) != 0;
    float* outb = biasf + (size_t)blockIdx.x * 4096;
    int mm = m < 49 ? m : 0;
    int i2 = mm / 7, j2 = mm % 7;
    int rm = (bH ? (i2 < 4 ? 1 : 2) : 0) * 3 + (bW ? (j2 < 4 ? 1 : 2) : 0);
#pragma unroll
    for (int ta = 0; ta < 4; ++ta) {
#pragma unroll
        for (int j = 0; j < 4; ++j) {
            int n = ta * 16 + hi * 4 + j;
            float v;
            if (n < 49 && m < 49) {
                int i1 = n / 7, j1 = n % 7;
                int rn = (bH ? (i1 < 4 ? 1 : 2) : 0) * 3 + (bW ? (j1 < 4 ? 1 : 2) : 0);
                v = rpbt[((i1 - i2 + 6) * 13 + (j1 - j2 + 6)) * 12 + h];
                if (rn != rm) v -= 100.0f;
            } else {
                v = -1e30f;
            }
            outb[(ta * 4 + j) * 256 + t] = v;
        }
    }
}

// LN1 + cyclic shift(-3,-3) + window partition. One wave per output row.
__global__ __launch_bounds__(256) void ln1_window_k(const float* __restrict__ x,
                                                    const float* __restrict__ g,
                                                    const float* __restrict__ bta,
                                                    bf16* __restrict__ ywin) {
    int wrow = blockIdx.x * 4 + (threadIdx.x >> 6);
    int lane = threadIdx.x & 63;
    int tok = wrow % 49, win = wrow / 49;
    int i = tok / 7, j = tok % 7;
    int wwi = win & 7, whi = (win >> 3) & 7, bi = win >> 6;
    int hs = (whi * 7 + i + 3) % 56;
    int ws_ = (wwi * 7 + j + 3) % 56;
    const float* xr = x + ((size_t)bi * 3136 + (size_t)hs * 56 + ws_) * 384;
    float v[6]; float s = 0.f, s2 = 0.f;
#pragma unroll
    for (int u = 0; u < 6; ++u) { float t = xr[lane + 64 * u]; v[u] = t; s += t; s2 += t * t; }
#pragma unroll
    for (int d = 1; d < 64; d <<= 1) { s += __shfl_xor(s, d); s2 += __shfl_xor(s2, d); }
    float mean = s * (1.0f / 384.0f);
    float var = s2 * (1.0f / 384.0f) - mean * mean;
    float rstd = rsqrtf(var + 1e-5f);
    bf16* yr = ywin + (size_t)wrow * 384;
#pragma unroll
    for (int u = 0; u < 6; ++u) {
        int c = lane + 64 * u;
        yr[c] = __float2bfloat16((v[u] - mean) * rstd * g[c] + bta[c]);
    }
}

// residual add (window-reverse + roll(+3,+3)) + LN2. x2 -> d_out (fp32), z -> bf16
__global__ __launch_bounds__(256) void resid_ln2_k(const float* __restrict__ x,
                                                   const bf16* __restrict__ proj,
                                                   const float* __restrict__ g,
                                                   const float* __restrict__ bta,
                                                   float* __restrict__ x2,
                                                   bf16* __restrict__ z) {
    int row = blockIdx.x * 4 + (threadIdx.x >> 6);
    int lane = threadIdx.x & 63;
    int bi = row / 3136; int hw = row % 3136;
    int h = hw / 56, w = hw % 56;
    int h2 = (h + 53) % 56, w2 = (w + 53) % 56;
    int prow = ((bi * 8 + h2 / 7) * 8 + w2 / 7) * 49 + (h2 % 7) * 7 + (w2 % 7);
    const float* xr = x + (size_t)row * 384;
    const bf16* pr = proj + (size_t)prow * 384;
    float* x2r = x2 + (size_t)row * 384;
    float v[6]; float s = 0.f, s2 = 0.f;
#pragma unroll
    for (int u = 0; u < 6; ++u) {
        int c = lane + 64 * u;
        float t = xr[c] + __bfloat162float(pr[c]);
        v[u] = t; s += t; s2 += t * t;
        x2r[c] = t;
    }
#pragma unroll
    for (int d = 1; d < 64; d <<= 1) { s += __shfl_xor(s, d); s2 += __shfl_xor(s2, d); }
    float mean = s * (1.0f / 384.0f);
    float var = s2 * (1.0f / 384.0f) - mean * mean;
    float rstd = rsqrtf(var + 1e-5f);
    bf16* zr = z + (size_t)row * 384;
#pragma unroll
    for (int u = 0; u < 6; ++u) {
        int c = lane + 64 * u;
        zr[c] = __float2bfloat16((v[u] - mean) * rstd * g[c] + bta[c]);
    }
}

// MFMA windowed attention (unchanged, round-10-verified).
__global__ __launch_bounds__(256) void attn_mfma_k(const bf16* __restrict__ qkv,
                                                   const float* __restrict__ biasf,
                                                   bf16* __restrict__ o) {
    __shared__ __align__(16) __bf16 vt_s[4][32 * 72];
    __shared__ __align__(16) __bf16 p_s[4][32 * 72];
    const int win = blockIdx.x;
    const int r = blockIdx.y;
    const int wave = threadIdx.x >> 6, lane = threadIdx.x & 63;
    const int lo = lane & 15, hi = lane >> 4;
    const int whi = (win >> 3) & 7, wwi = win & 7;
    const int wt = ((whi == 7) ? 2 : 0) + ((wwi == 7) ? 1 : 0);
    __bf16* vt_w = vt_s[wave];
    __bf16* p_w = p_s[wave];
    const int h = r * 4 + wave;
    const bf16* qbase = qkv + (size_t)win * 49 * 1152 + h * 32;
    const float* btile = biasf + (size_t)(wt * 12 + h) * 4096;
    bf16x8 zf = {};

    {
        int m = lane;
        bf16x8 vrow[4];
#pragma unroll
        for (int d8 = 0; d8 < 4; ++d8)
            vrow[d8] = (m < 49) ? *(const bf16x8*)(qbase + (size_t)m * 1152 + 768 + d8 * 8) : zf;
#pragma unroll
        for (int d8 = 0; d8 < 4; ++d8)
#pragma unroll
            for (int e = 0; e < 8; ++e)
                vt_w[(d8 * 8 + e) * 72 + m] = vrow[d8][e];
    }
    bf16x8 aq[4], bk[4];
    const int kq = hi * 8;
#pragma unroll
    for (int ta = 0; ta < 4; ++ta) {
        int n = ta * 16 + lo;
        aq[ta] = (n < 49) ? *(const bf16x8*)(qbase + (size_t)n * 1152 + kq) : zf;
        bk[ta] = (n < 49) ? *(const bf16x8*)(qbase + (size_t)n * 1152 + 384 + kq) : zf;
    }
    f32x4 acc[4][4] = {};
#pragma unroll
    for (int ta = 0; ta < 4; ++ta)
#pragma unroll
        for (int tb = 0; tb < 4; ++tb)
            acc[ta][tb] = __builtin_amdgcn_mfma_f32_16x16x32_bf16(aq[ta], bk[tb], acc[ta][tb], 0, 0, 0);
#pragma unroll
    for (int ta = 0; ta < 4; ++ta) {
#pragma unroll
        for (int j = 0; j < 4; ++j) {
            float4 b4 = *(const float4*)(btile + (ta * 4 + j) * 256 + lane * 4);
            acc[ta][0][j] = fmaf(acc[ta][0][j], 0.17677669529663687f, b4.x);
            acc[ta][1][j] = fmaf(acc[ta][1][j], 0.17677669529663687f, b4.y);
            acc[ta][2][j] = fmaf(acc[ta][2][j], 0.17677669529663687f, b4.z);
            acc[ta][3][j] = fmaf(acc[ta][3][j], 0.17677669529663687f, b4.w);
        }
    }
    bf16x8 vb[2][2];
#pragma unroll
    for (int kb = 0; kb < 2; ++kb)
#pragma unroll
        for (int tb = 0; tb < 2; ++tb)
            vb[kb][tb] = *(const bf16x8*)(vt_w + (tb * 16 + lo) * 72 + kb * 32 + hi * 8);

    f32x4 oacc[4][2] = {};
#pragma unroll
    for (int half = 0; half < 2; ++half) {
#pragma unroll
        for (int tq = 0; tq < 2; ++tq) {
            int ta = half * 2 + tq;
#pragma unroll
            for (int j = 0; j < 4; ++j) {
                float mx = fmaxf(fmaxf(acc[ta][0][j], acc[ta][1][j]),
                                 fmaxf(acc[ta][2][j], acc[ta][3][j]));
                mx = fmaxf(mx, __shfl_xor(mx, 1));
                mx = fmaxf(mx, __shfl_xor(mx, 2));
                mx = fmaxf(mx, __shfl_xor(mx, 4));
                mx = fmaxf(mx, __shfl_xor(mx, 8));
                float e0 = __expf(acc[ta][0][j] - mx);
                float e1 = __expf(acc[ta][1][j] - mx);
                float e2 = __expf(acc[ta][2][j] - mx);
                float e3 = __expf(acc[ta][3][j] - mx);
                float sm = e0 + e1 + e2 + e3;
                sm += __shfl_xor(sm, 1);
                sm += __shfl_xor(sm, 2);
                sm += __shfl_xor(sm, 4);
                sm += __shfl_xor(sm, 8);
                float inv = __builtin_amdgcn_rcpf(sm);
                int nl = tq * 16 + hi * 4 + j;
                p_w[nl * 72 + lo]      = (__bf16)(e0 * inv);
                p_w[nl * 72 + 16 + lo] = (__bf16)(e1 * inv);
                p_w[nl * 72 + 32 + lo] = (__bf16)(e2 * inv);
                p_w[nl * 72 + 48 + lo] = (__bf16)(e3 * inv);
            }
        }
#pragma unroll
        for (int kb = 0; kb < 2; ++kb) {
#pragma unroll
            for (int tq = 0; tq < 2; ++tq) {
                bf16x8 pa = *(const bf16x8*)(p_w + (tq * 16 + lo) * 72 + kb * 32 + hi * 8);
#pragma unroll
                for (int tb = 0; tb < 2; ++tb)
                    oacc[half * 2 + tq][tb] =
                        __builtin_amdgcn_mfma_f32_16x16x32_bf16(pa, vb[kb][tb], oacc[half * 2 + tq][tb], 0, 0, 0);
            }
        }
    }
    bf16* obase = o + (size_t)win * 49 * 384 + h * 32;
#pragma unroll
    for (int ta = 0; ta < 4; ++ta) {
#pragma unroll
        for (int j = 0; j < 4; ++j) {
            int n = ta * 16 + hi * 4 + j;
            if (n < 49) {
#pragma unroll
                for (int tb = 0; tb < 2; ++tb)
                    obase[(size_t)n * 384 + tb * 16 + lo] = __float2bfloat16(oacc[ta][tb][j]);
            }
        }
    }
}

// R12-proven GEMM template. WN=2: 256thr 128x64; WN=4: 512thr 128x128.
template <int K, int N, int WN, int EPI>
__global__ __launch_bounds__(WN * 128, 8 - WN) void gemm_bt(const bf16* __restrict__ A,
                                                            const bf16* __restrict__ W,
                                                            const float* __restrict__ bias,
                                                            void* __restrict__ Cout) {
    constexpr int T = WN * 128;
    constexpr int BN = WN * 32;
    __shared__ __align__(16) bf16 lds_a[128 * 64];
    __shared__ __align__(16) bf16 lds_b[BN * 64];
    const int t = threadIdx.x;
    const int wave = t >> 6, lane = t & 63;
    const int gdx = gridDim.x;
    int flat = blockIdx.y * gdx + blockIdx.x;
    int q = (gdx * gridDim.y) >> 3;
    int work = (flat & 7) * q + (flat >> 3);
    const int n0 = (work % gdx) * BN, m0 = (work / gdx) * 128;
    const int wm = wave / WN, wn = wave % WN;
    const int fr = lane & 15, hi = lane >> 4;
    const int srow = t >> 3;
    const int gslot = (t & 7) ^ (srow & 7);
    const bf16* abase = A + (size_t)(m0 + srow) * K + gslot * 8;
    const bf16* bbase = W + (size_t)(n0 + srow) * K + gslot * 8;
    char* la = (char*)lds_a + t * 16;
    char* lb = (char*)lds_b + t * 16;
    const int fp = fr & 7;
    const char* ra0 = (const char*)lds_a + (wm * 64 + fr) * 128 + (hi ^ fp) * 16;
    const char* ra1 = (const char*)lds_a + (wm * 64 + fr) * 128 + ((4 + hi) ^ fp) * 16;
    const char* rb0 = (const char*)lds_b + (wn * 32 + fr) * 128 + (hi ^ fp) * 16;
    const char* rb1 = (const char*)lds_b + (wn * 32 + fr) * 128 + ((4 + hi) ^ fp) * 16;
    f32x4 acc[4][2] = {};
#pragma unroll
    for (int kt = 0; kt < K; kt += 64) {
        if (kt > 0) __syncthreads();
#pragma unroll
        for (int i = 0; i < 1024 / T; ++i)
            async16(la + i * T * 16, abase + (size_t)i * (T >> 3) * K + kt);
#pragma unroll
        for (int i = 0; i < BN * 8 / T; ++i)
            async16(lb + i * T * 16, bbase + (size_t)i * (T >> 3) * K + kt);
        __syncthreads();
        bf16x8 af[4], bfr[2];
#pragma unroll
        for (int mi = 0; mi < 4; ++mi) af[mi] = *(const bf16x8*)(ra0 + mi * 2048);
#pragma unroll
        for (int ni = 0; ni < 2; ++ni) bfr[ni] = *(const bf16x8*)(rb0 + ni * 2048);
#pragma unroll
        for (int mi = 0; mi < 4; ++mi)
#pragma unroll
            for (int ni = 0; ni < 2; ++ni)
                acc[mi][ni] = __builtin_amdgcn_mfma_f32_16x16x32_bf16(bfr[ni], af[mi], acc[mi][ni], 0, 0, 0);
#pragma unroll
        for (int mi = 0; mi < 4; ++mi) af[mi] = *(const bf16x8*)(ra1 + mi * 2048);
#pragma unroll
        for (int ni = 0; ni < 2; ++ni) bfr[ni] = *(const bf16x8*)(rb1 + ni * 2048);
#pragma unroll
        for (int mi = 0; mi < 4; ++mi)
#pragma unroll
            for (int ni = 0; ni < 2; ++ni)
                acc[mi][ni] = __builtin_amdgcn_mfma_f32_16x16x32_bf16(bfr[ni], af[mi], acc[mi][ni], 0, 0, 0);
    }
    const int rq4 = hi * 4;
    const int ncol = n0 + wn * 32 + rq4;
    const size_t cbase = (size_t)(m0 + wm * 64 + fr) * N + ncol;
    const float* pb = bias ? bias + ncol : nullptr;
#pragma unroll
    for (int mi = 0; mi < 4; ++mi) {
#pragma unroll
        for (int ni = 0; ni < 2; ++ni) {
            float v0 = acc[mi][ni][0], v1 = acc[mi][ni][1];
            float v2 = acc[mi][ni][2], v3 = acc[mi][ni][3];
            if (pb) {
                float4 b4 = *(const float4*)(pb + ni * 16);
                v0 += b4.x; v1 += b4.y; v2 += b4.z; v3 += b4.w;
            }
            if (EPI == 1) { v0 = gelu_f(v0); v1 = gelu_f(v1); v2 = gelu_f(v2); v3 = gelu_f(v3); }
            if (EPI == 2) {
                float4* p = (float4*)((float*)Cout + cbase + (size_t)mi * 16 * N + ni * 16);
                float4 o = *p;
                o.x += v0; o.y += v1; o.z += v2; o.w += v3;
                *p = o;
            } else {
                bf16x4v st = { (__bf16)v0, (__bf16)v1, (__bf16)v2, (__bf16)v3 };
                *(bf16x4v*)((bf16*)Cout + cbase + (size_t)mi * 16 * N + ni * 16) = st;
            }
        }
    }
}

// Fused MLP middle: C[M,192] = gelu(A[M,192] @ U^T + b1) @ V2^T.
// 64-row blocks: LDS 24+16 = 40 KB -> 4 blocks/CU (was 80 KB / 2 blocks,
// Occupancy 31% -- the R14 limiter). Grid 1568. 4 waves share all 64 rows;
// wave wn owns hidden-cols [32wn,32wn+32) in GEMM1, out-cols [48wn,48wn+48)
// in GEMM2. Weights U/V2 are L2-resident; H never touches HBM.
__global__ __launch_bounds__(256, 4) void mlp_mid_k(const bf16* __restrict__ A,
                                                    const bf16* __restrict__ U,
                                                    const bf16* __restrict__ V2,
                                                    const float* __restrict__ b1,
                                                    bf16* __restrict__ Cout) {
    __shared__ __align__(16) bf16 lds_a[64 * 192];    // 24 KB
    __shared__ __align__(16) bf16 lds_h[64 * 128];    // 16 KB
    const int t = threadIdx.x;
    const int wave = t >> 6, lane = t & 63;
    const int wn = wave;
    const int fr = lane & 15, hi = lane >> 4;
    const int fp = fr & 7;
    const int m0 = blockIdx.x * 64;
    // stage A[64][192]: 1536 16B units, 6 per thread
#pragma unroll
    for (int i = 0; i < 6; ++i) {
        int u = i * 256 + t;
        int row = u / 24, slot = u % 24;
        int gslot = slot ^ (row & 7);
        async16((char*)lds_a + u * 16, A + (size_t)(m0 + row) * 192 + gslot * 8);
    }
    __syncthreads();

    f32x4 acc2[4][3] = {};
    const bf16* ub = U + (size_t)(wn * 32 + fr) * 192 + hi * 8;
    const bf16* vb = V2 + (size_t)(wn * 48 + fr) * 1536 + hi * 8;

    for (int hc = 0; hc < 12; ++hc) {
        // ---- GEMM1: H[0:64][wn*32 : wn*32+32] over K=192 ----
        f32x4 acc1[4][2] = {};
#pragma unroll
        for (int kk = 0; kk < 6; ++kk) {
            bf16x8 af[4], bu[2];
#pragma unroll
            for (int mi = 0; mi < 4; ++mi) {
                int row = mi * 16 + fr;
                af[mi] = *(const bf16x8*)((const char*)lds_a + row * 384 + ((kk * 4 + hi) ^ fp) * 16);
            }
#pragma unroll
            for (int nn = 0; nn < 2; ++nn)
                bu[nn] = *(const bf16x8*)(ub + (size_t)(hc * 128 + nn * 16) * 192 + kk * 32);
#pragma unroll
            for (int mi = 0; mi < 4; ++mi)
#pragma unroll
                for (int nn = 0; nn < 2; ++nn)
                    acc1[mi][nn] = __builtin_amdgcn_mfma_f32_16x16x32_bf16(bu[nn], af[mi], acc1[mi][nn], 0, 0, 0);
        }
        if (hc > 0) __syncthreads();   // all waves done reading previous H
        // ---- gelu + bias -> H LDS (byte ^= (m&7)<<4 within row) ----
#pragma unroll
        for (int nn = 0; nn < 2; ++nn) {
            float4 b4 = *(const float4*)(b1 + hc * 128 + wn * 32 + nn * 16 + hi * 4);
#pragma unroll
            for (int mi = 0; mi < 4; ++mi) {
                int mrow = mi * 16 + fr;
                float v0 = gelu_f(acc1[mi][nn][0] + b4.x);
                float v1 = gelu_f(acc1[mi][nn][1] + b4.y);
                float v2 = gelu_f(acc1[mi][nn][2] + b4.z);
                float v3 = gelu_f(acc1[mi][nn][3] + b4.w);
                bf16x4v st = { (__bf16)v0, (__bf16)v1, (__bf16)v2, (__bf16)v3 };
                int hb = (wn * 64 + nn * 32 + hi * 8) ^ ((mrow & 7) << 4);
                *(bf16x4v*)((char*)lds_h + mrow * 256 + hb) = st;
            }
        }
        __syncthreads();
        // ---- GEMM2: C[0:64][wn*48 : wn*48+48] += H[0:64][0:128] @ V2c^T ----
#pragma unroll
        for (int kk = 0; kk < 4; ++kk) {
            bf16x8 af2[4], bv[3];
#pragma unroll
            for (int mi = 0; mi < 4; ++mi) {
                int mrow = mi * 16 + fr;
                int kb = (kk * 64 + hi * 16) ^ ((mrow & 7) << 4);
                af2[mi] = *(const bf16x8*)((const char*)lds_h + mrow * 256 + kb);
            }
#pragma unroll
            for (int tn = 0; tn < 3; ++tn)
                bv[tn] = *(const bf16x8*)(vb + (size_t)(tn * 16) * 1536 + hc * 128 + kk * 32);
#pragma unroll
            for (int mi = 0; mi < 4; ++mi)
#pragma unroll
                for (int tn = 0; tn < 3; ++tn)
                    acc2[mi][tn] = __builtin_amdgcn_mfma_f32_16x16x32_bf16(bv[tn], af2[mi], acc2[mi][tn], 0, 0, 0);
        }
    }
    // ---- epilogue: C[m][n], n = wn*48 + tn*16 + hi*4 ----
    const size_t cbase = (size_t)(m0 + fr) * 192 + wn * 48 + hi * 4;
#pragma unroll
    for (int mi = 0; mi < 4; ++mi) {
#pragma unroll
        for (int tn = 0; tn < 3; ++tn) {
            bf16x4v st = { (__bf16)acc2[mi][tn][0], (__bf16)acc2[mi][tn][1],
                           (__bf16)acc2[mi][tn][2], (__bf16)acc2[mi][tn][3] };
            *(bf16x4v*)(Cout + cbase + (size_t)mi * 16 * 192 + tn * 16) = st;
        }
    }
}

extern "C" void kernel_launch(void* const* d_in, const int* in_sizes, int n_in,
                              void* d_out, int out_size, void* d_ws, size_t ws_size,
                              hipStream_t stream) {
    const float* x      = (const float*)d_in[0];
    const float* n1g    = (const float*)d_in[1];
    const float* n1b    = (const float*)d_in[2];
    const float* rpbt   = (const float*)d_in[3];
    const float* qkv_v  = (const float*)d_in[4];
    const float* qkv_u  = (const float*)d_in[5];
    const float* qkv_b  = (const float*)d_in[6];
    const float* proj_v = (const float*)d_in[7];
    const float* proj_u = (const float*)d_in[8];
    const float* proj_b = (const float*)d_in[9];
    const float* n2g    = (const float*)d_in[10];
    const float* n2b    = (const float*)d_in[11];
    const float* fc1_v  = (const float*)d_in[12];
    const float* fc1_u  = (const float*)d_in[13];
    const float* fc1_b  = (const float*)d_in[14];
    const float* fc2_v  = (const float*)d_in[15];
    const float* fc2_u  = (const float*)d_in[16];
    const float* fc2_b  = (const float*)d_in[17];

    char* ws = (char*)d_ws;
    bf16* wb = (bf16*)ws;
    bf16* w_qkv_v  = wb;
    bf16* w_qkv_u  = wb + 73728;
    bf16* w_proj_v = wb + 294912;
    bf16* w_proj_u = wb + 368640;
    bf16* w_fc1_v  = wb + 442368;
    bf16* w_fc1_u  = wb + 516096;
    bf16* w_fc2_v  = wb + 811008;
    bf16* w_fc2_u  = wb + 1105920;
    bf16* w_proj_m = wb + 1179648;             // 384x384 merged proj
    float* biasf   = (float*)(ws + 3145728);   // 768 KB
    size_t off = (size_t)4 << 20;
    bf16* R1 = (bf16*)(ws + off); off += (size_t)MROWS * 1536 * 2;   // qkv / proj-out / mlp-out
    bf16* R2 = (bf16*)(ws + off); off += (size_t)MROWS * 384 * 2;    // ywin / o / z
    bf16* R3 = (bf16*)(ws + off);                                    // rank-192 temps
    float* out = (float*)d_out;

    Cvt8 c;
    c.s[0] = qkv_v;  c.d[0] = w_qkv_v;  c.n[0] = 73728;
    c.s[1] = qkv_u;  c.d[1] = w_qkv_u;  c.n[1] = 221184;
    c.s[2] = proj_v; c.d[2] = w_proj_v; c.n[2] = 73728;
    c.s[3] = proj_u; c.d[3] = w_proj_u; c.n[3] = 73728;
    c.s[4] = fc1_v;  c.d[4] = w_fc1_v;  c.n[4] = 73728;
    c.s[5] = fc1_u;  c.d[5] = w_fc1_u;  c.n[5] = 294912;
    c.s[6] = fc2_v;  c.d[6] = w_fc2_v;  c.n[6] = 294912;
    c.s[7] = fc2_u;  c.d[7] = w_fc2_u;  c.n[7] = 73728;
    cvt8_k<<<dim3(288, 8), 256, 0, stream>>>(c);
    bias_pre_k<<<48, 256, 0, stream>>>(rpbt, biasf);
    wmerge_k<<<384, 384, 0, stream>>>(proj_u, proj_v, w_proj_m);

    ln1_window_k<<<MROWS / 4, 256, 0, stream>>>(x, n1g, n1b, R2);
    gemm_bt<384, 192, 2, 0><<<dim3(3, 784), 256, 0, stream>>>(R2, w_qkv_v, nullptr, R3);
    gemm_bt<192, 1152, 4, 0><<<dim3(9, 784), 512, 0, stream>>>(R3, w_qkv_u, qkv_b, R1);
    attn_mfma_k<<<dim3(2048, 3), 256, 0, stream>>>(R1, biasf, R2);
    gemm_bt<384, 384, 4, 0><<<dim3(3, 784), 512, 0, stream>>>(R2, w_proj_m, proj_b, R1);
    resid_ln2_k<<<MROWS / 4, 256, 0, stream>>>(x, R1, n2g, n2b, out, R2);
    gemm_bt<384, 192, 2, 0><<<dim3(3, 784), 256, 0, stream>>>(R2, w_fc1_v, nullptr, R3);
    mlp_mid_k<<<1568, 256, 0, stream>>>(R3, w_fc1_u, w_fc2_v, fc1_b, R1);
    gemm_bt<192, 384, 4, 2><<<dim3(3, 784), 512, 0, stream>>>(R1, w_fc2_u, fc2_b, out);
}

// Round 16
// 810.142 us; speedup vs baseline: 1.1521x; 1.0007x over previous
//
#include <hip/hip_runtime.h>
#include <hip/hip_bf16.h>

using bf16 = __hip_bfloat16;
typedef __bf16 bf16x8 __attribute__((ext_vector_type(8)));
typedef __bf16 bf16x4v __attribute__((ext_vector_type(4)));
typedef float f32x4 __attribute__((ext_vector_type(4)));

#define MROWS 100352   // 2048 windows * 49 tokens = 32*3136

__device__ __forceinline__ void async16(void* l, const void* g) {
    void* gg = const_cast<void*>(g);
    __builtin_amdgcn_global_load_lds((__attribute__((address_space(1))) void*)gg,
                                     (__attribute__((address_space(3))) void*)l, 16, 0, 0);
}

// tanh-gelu via sigmoid identity: 0.5x(1+tanh(u)) == x*sigmoid(2u)
__device__ __forceinline__ float gelu_f(float x) {
    float u = x * fmaf(0.044715f * x, x, 1.0f);
    float e = __expf(-1.5957691216057308f * u);
    return x * __builtin_amdgcn_rcpf(1.0f + e);
}

struct Cvt8 { const float* s[8]; bf16* d[8]; int n[8]; };

__global__ __launch_bounds__(256) void cvt8_k(Cvt8 c) {
    int seg = blockIdx.y;
    int i4 = (blockIdx.x * 256 + threadIdx.x) * 4;
    if (i4 < c.n[seg]) {
        float4 v = *(const float4*)(c.s[seg] + i4);
        bf16* d = c.d[seg] + i4;
        d[0] = __float2bfloat16(v.x);
        d[1] = __float2bfloat16(v.y);
        d[2] = __float2bfloat16(v.z);
        d[3] = __float2bfloat16(v.w);
    }
}

// merged proj weight: Wm[384][384] = proj_u(384x192) @ proj_v(192x384), bf16.
__global__ __launch_bounds__(384) void wmerge_k(const float* __restrict__ u,
                                                const float* __restrict__ v,
                                                bf16* __restrict__ wm) {
    int o = blockIdx.x, i = threadIdx.x;
    const float* ur = u + o * 192;
    float acc = 0.f;
    for (int r = 0; r < 192; ++r) acc = fmaf(ur[r], v[r * 384 + i], acc);
    wm[o * 384 + i] = __float2bfloat16(acc);
}

// Precompute attn bias (rpb + shift-mask) in C-fragment layout.
__global__ __launch_bounds__(256) void bias_pre_k(const float* __restrict__ rpbt,
                                                  float* __restrict__ biasf) {
    int wt = blockIdx.x / 12, h = blockIdx.x % 12;
    int t = threadIdx.x;
    int lane = t >> 2, tb = t & 3;
    int hi = lane >> 4, lo = lane & 15;
    int m = tb * 16 + lo;
    bool bH = (wt & 2) != 0, bW = (wt & 1) != 0;
    float* outb = biasf + (size_t)blockIdx.x * 4096;
    int mm = m < 49 ? m : 0;
    int i2 = mm / 7, j2 = mm % 7;
    int rm = (bH ? (i2 < 4 ? 1 : 2) : 0) * 3 + (bW ? (j2 < 4 ? 1 : 2) : 0);
#pragma unroll
    for (int ta = 0; ta < 4; ++ta) {
#pragma unroll
        for (int j = 0; j < 4; ++j) {
            int n = ta * 16 + hi * 4 + j;
            float v;
            if (n < 49 && m < 49) {
                int i1 = n / 7, j1 = n % 7;
                int rn = (bH ? (i1 < 4 ? 1 : 2) : 0) * 3 + (bW ? (j1 < 4 ? 1 : 2) : 0);
                v = rpbt[((i1 - i2 + 6) * 13 + (j1 - j2 + 6)) * 12 + h];
                if (rn != rm) v -= 100.0f;
            } else {
                v = -1e30f;
            }
            outb[(ta * 4 + j) * 256 + t] = v;
        }
    }
}

// LN1 + cyclic shift(-3,-3) + window partition. One wave per output row.
__global__ __launch_bounds__(256) void ln1_window_k(const float* __restrict__ x,
                                                    const float* __restrict__ g,
                                                    const float* __restrict__ bta,
                                                    bf16* __restrict__ ywin) {
    int wrow = blockIdx.x * 4 + (threadIdx.x >> 6);
    int lane = threadIdx.x & 63;
    int tok = wrow % 49, win = wrow / 49;
    int i = tok / 7, j = tok % 7;
    int wwi = win & 7, whi = (win >> 3) & 7, bi = win >> 6;
    int hs = (whi * 7 + i + 3) % 56;
    int ws_ = (wwi * 7 + j + 3) % 56;
    const float* xr = x + ((size_t)bi * 3136 + (size_t)hs * 56 + ws_) * 384;
    float v[6]; float s = 0.f, s2 = 0.f;
#pragma unroll
    for (int u = 0; u < 6; ++u) { float t = xr[lane + 64 * u]; v[u] = t; s += t; s2 += t * t; }
#pragma unroll
    for (int d = 1; d < 64; d <<= 1) { s += __shfl_xor(s, d); s2 += __shfl_xor(s2, d); }
    float mean = s * (1.0f / 384.0f);
    float var = s2 * (1.0f / 384.0f) - mean * mean;
    float rstd = rsqrtf(var + 1e-5f);
    bf16* yr = ywin + (size_t)wrow * 384;
#pragma unroll
    for (int u = 0; u < 6; ++u) {
        int c = lane + 64 * u;
        yr[c] = __float2bfloat16((v[u] - mean) * rstd * g[c] + bta[c]);
    }
}

// residual add (window-reverse + roll(+3,+3)) + LN2. x2 -> d_out (fp32), z -> bf16
__global__ __launch_bounds__(256) void resid_ln2_k(const float* __restrict__ x,
                                                   const bf16* __restrict__ proj,
                                                   const float* __restrict__ g,
                                                   const float* __restrict__ bta,
                                                   float* __restrict__ x2,
                                                   bf16* __restrict__ z) {
    int row = blockIdx.x * 4 + (threadIdx.x >> 6);
    int lane = threadIdx.x & 63;
    int bi = row / 3136; int hw = row % 3136;
    int h = hw / 56, w = hw % 56;
    int h2 = (h + 53) % 56, w2 = (w + 53) % 56;
    int prow = ((bi * 8 + h2 / 7) * 8 + w2 / 7) * 49 + (h2 % 7) * 7 + (w2 % 7);
    const float* xr = x + (size_t)row * 384;
    const bf16* pr = proj + (size_t)prow * 384;
    float* x2r = x2 + (size_t)row * 384;
    float v[6]; float s = 0.f, s2 = 0.f;
#pragma unroll
    for (int u = 0; u < 6; ++u) {
        int c = lane + 64 * u;
        float t = xr[c] + __bfloat162float(pr[c]);
        v[u] = t; s += t; s2 += t * t;
        x2r[c] = t;
    }
#pragma unroll
    for (int d = 1; d < 64; d <<= 1) { s += __shfl_xor(s, d); s2 += __shfl_xor(s2, d); }
    float mean = s * (1.0f / 384.0f);
    float var = s2 * (1.0f / 384.0f) - mean * mean;
    float rstd = rsqrtf(var + 1e-5f);
    bf16* zr = z + (size_t)row * 384;
#pragma unroll
    for (int u = 0; u < 6; ++u) {
        int c = lane + 64 * u;
        zr[c] = __float2bfloat16((v[u] - mean) * rstd * g[c] + bta[c]);
    }
}

// MFMA windowed attention (unchanged, round-10-verified).
__global__ __launch_bounds__(256) void attn_mfma_k(const bf16* __restrict__ qkv,
                                                   const float* __restrict__ biasf,
                                                   bf16* __restrict__ o) {
    __shared__ __align__(16) __bf16 vt_s[4][32 * 72];
    __shared__ __align__(16) __bf16 p_s[4][32 * 72];
    const int win = blockIdx.x;
    const int r = blockIdx.y;
    const int wave = threadIdx.x >> 6, lane = threadIdx.x & 63;
    const int lo = lane & 15, hi = lane >> 4;
    const int whi = (win >> 3) & 7, wwi = win & 7;
    const int wt = ((whi == 7) ? 2 : 0) + ((wwi == 7) ? 1 : 0);
    __bf16* vt_w = vt_s[wave];
    __bf16* p_w = p_s[wave];
    const int h = r * 4 + wave;
    const bf16* qbase = qkv + (size_t)win * 49 * 1152 + h * 32;
    const float* btile = biasf + (size_t)(wt * 12 + h) * 4096;
    bf16x8 zf = {};

    {
        int m = lane;
        bf16x8 vrow[4];
#pragma unroll
        for (int d8 = 0; d8 < 4; ++d8)
            vrow[d8] = (m < 49) ? *(const bf16x8*)(qbase + (size_t)m * 1152 + 768 + d8 * 8) : zf;
#pragma unroll
        for (int d8 = 0; d8 < 4; ++d8)
#pragma unroll
            for (int e = 0; e < 8; ++e)
                vt_w[(d8 * 8 + e) * 72 + m] = vrow[d8][e];
    }
    bf16x8 aq[4], bk[4];
    const int kq = hi * 8;
#pragma unroll
    for (int ta = 0; ta < 4; ++ta) {
        int n = ta * 16 + lo;
        aq[ta] = (n < 49) ? *(const bf16x8*)(qbase + (size_t)n * 1152 + kq) : zf;
        bk[ta] = (n < 49) ? *(const bf16x8*)(qbase + (size_t)n * 1152 + 384 + kq) : zf;
    }
    f32x4 acc[4][4] = {};
#pragma unroll
    for (int ta = 0; ta < 4; ++ta)
#pragma unroll
        for (int tb = 0; tb < 4; ++tb)
            acc[ta][tb] = __builtin_amdgcn_mfma_f32_16x16x32_bf16(aq[ta], bk[tb], acc[ta][tb], 0, 0, 0);
#pragma unroll
    for (int ta = 0; ta < 4; ++ta) {
#pragma unroll
        for (int j = 0; j < 4; ++j) {
            float4 b4 = *(const float4*)(btile + (ta * 4 + j) * 256 + lane * 4);
            acc[ta][0][j] = fmaf(acc[ta][0][j], 0.17677669529663687f, b4.x);
            acc[ta][1][j] = fmaf(acc[ta][1][j], 0.17677669529663687f, b4.y);
            acc[ta][2][j] = fmaf(acc[ta][2][j], 0.17677669529663687f, b4.z);
            acc[ta][3][j] = fmaf(acc[ta][3][j], 0.17677669529663687f, b4.w);
        }
    }
    bf16x8 vb[2][2];
#pragma unroll
    for (int kb = 0; kb < 2; ++kb)
#pragma unroll
        for (int tb = 0; tb < 2; ++tb)
            vb[kb][tb] = *(const bf16x8*)(vt_w + (tb * 16 + lo) * 72 + kb * 32 + hi * 8);

    f32x4 oacc[4][2] = {};
#pragma unroll
    for (int half = 0; half < 2; ++half) {
#pragma unroll
        for (int tq = 0; tq < 2; ++tq) {
            int ta = half * 2 + tq;
#pragma unroll
            for (int j = 0; j < 4; ++j) {
                float mx = fmaxf(fmaxf(acc[ta][0][j], acc[ta][1][j]),
                                 fmaxf(acc[ta][2][j], acc[ta][3][j]));
                mx = fmaxf(mx, __shfl_xor(mx, 1));
                mx = fmaxf(mx, __shfl_xor(mx, 2));
                mx = fmaxf(mx, __shfl_xor(mx, 4));
                mx = fmaxf(mx, __shfl_xor(mx, 8));
                float e0 = __expf(acc[ta][0][j] - mx);
                float e1 = __expf(acc[ta][1][j] - mx);
                float e2 = __expf(acc[ta][2][j] - mx);
                float e3 = __expf(acc[ta][3][j] - mx);
                float sm = e0 + e1 + e2 + e3;
                sm += __shfl_xor(sm, 1);
                sm += __shfl_xor(sm, 2);
                sm += __shfl_xor(sm, 4);
                sm += __shfl_xor(sm, 8);
                float inv = __builtin_amdgcn_rcpf(sm);
                int nl = tq * 16 + hi * 4 + j;
                p_w[nl * 72 + lo]      = (__bf16)(e0 * inv);
                p_w[nl * 72 + 16 + lo] = (__bf16)(e1 * inv);
                p_w[nl * 72 + 32 + lo] = (__bf16)(e2 * inv);
                p_w[nl * 72 + 48 + lo] = (__bf16)(e3 * inv);
            }
        }
#pragma unroll
        for (int kb = 0; kb < 2; ++kb) {
#pragma unroll
            for (int tq = 0; tq < 2; ++tq) {
                bf16x8 pa = *(const bf16x8*)(p_w + (tq * 16 + lo) * 72 + kb * 32 + hi * 8);
#pragma unroll
                for (int tb = 0; tb < 2; ++tb)
                    oacc[half * 2 + tq][tb] =
                        __builtin_amdgcn_mfma_f32_16x16x32_bf16(pa, vb[kb][tb], oacc[half * 2 + tq][tb], 0, 0, 0);
            }
        }
    }
    bf16* obase = o + (size_t)win * 49 * 384 + h * 32;
#pragma unroll
    for (int ta = 0; ta < 4; ++ta) {
#pragma unroll
        for (int j = 0; j < 4; ++j) {
            int n = ta * 16 + hi * 4 + j;
            if (n < 49) {
#pragma unroll
                for (int tb = 0; tb < 2; ++tb)
                    obase[(size_t)n * 384 + tb * 16 + lo] = __float2bfloat16(oacc[ta][tb][j]);
            }
        }
    }
}

// R12-proven GEMM template. WN=2: 256thr 128x64; WN=4: 512thr 128x128.
template <int K, int N, int WN, int EPI>
__global__ __launch_bounds__(WN * 128, 8 - WN) void gemm_bt(const bf16* __restrict__ A,
                                                            const bf16* __restrict__ W,
                                                            const float* __restrict__ bias,
                                                            void* __restrict__ Cout) {
    constexpr int T = WN * 128;
    constexpr int BN = WN * 32;
    __shared__ __align__(16) bf16 lds_a[128 * 64];
    __shared__ __align__(16) bf16 lds_b[BN * 64];
    const int t = threadIdx.x;
    const int wave = t >> 6, lane = t & 63;
    const int gdx = gridDim.x;
    int flat = blockIdx.y * gdx + blockIdx.x;
    int q = (gdx * gridDim.y) >> 3;
    int work = (flat & 7) * q + (flat >> 3);
    const int n0 = (work % gdx) * BN, m0 = (work / gdx) * 128;
    const int wm = wave / WN, wn = wave % WN;
    const int fr = lane & 15, hi = lane >> 4;
    const int srow = t >> 3;
    const int gslot = (t & 7) ^ (srow & 7);
    const bf16* abase = A + (size_t)(m0 + srow) * K + gslot * 8;
    const bf16* bbase = W + (size_t)(n0 + srow) * K + gslot * 8;
    char* la = (char*)lds_a + t * 16;
    char* lb = (char*)lds_b + t * 16;
    const int fp = fr & 7;
    const char* ra0 = (const char*)lds_a + (wm * 64 + fr) * 128 + (hi ^ fp) * 16;
    const char* ra1 = (const char*)lds_a + (wm * 64 + fr) * 128 + ((4 + hi) ^ fp) * 16;
    const char* rb0 = (const char*)lds_b + (wn * 32 + fr) * 128 + (hi ^ fp) * 16;
    const char* rb1 = (const char*)lds_b + (wn * 32 + fr) * 128 + ((4 + hi) ^ fp) * 16;
    f32x4 acc[4][2] = {};
#pragma unroll
    for (int kt = 0; kt < K; kt += 64) {
        if (kt > 0) __syncthreads();
#pragma unroll
        for (int i = 0; i < 1024 / T; ++i)
            async16(la + i * T * 16, abase + (size_t)i * (T >> 3) * K + kt);
#pragma unroll
        for (int i = 0; i < BN * 8 / T; ++i)
            async16(lb + i * T * 16, bbase + (size_t)i * (T >> 3) * K + kt);
        __syncthreads();
        bf16x8 af[4], bfr[2];
#pragma unroll
        for (int mi = 0; mi < 4; ++mi) af[mi] = *(const bf16x8*)(ra0 + mi * 2048);
#pragma unroll
        for (int ni = 0; ni < 2; ++ni) bfr[ni] = *(const bf16x8*)(rb0 + ni * 2048);
#pragma unroll
        for (int mi = 0; mi < 4; ++mi)
#pragma unroll
            for (int ni = 0; ni < 2; ++ni)
                acc[mi][ni] = __builtin_amdgcn_mfma_f32_16x16x32_bf16(bfr[ni], af[mi], acc[mi][ni], 0, 0, 0);
#pragma unroll
        for (int mi = 0; mi < 4; ++mi) af[mi] = *(const bf16x8*)(ra1 + mi * 2048);
#pragma unroll
        for (int ni = 0; ni < 2; ++ni) bfr[ni] = *(const bf16x8*)(rb1 + ni * 2048);
#pragma unroll
        for (int mi = 0; mi < 4; ++mi)
#pragma unroll
            for (int ni = 0; ni < 2; ++ni)
                acc[mi][ni] = __builtin_amdgcn_mfma_f32_16x16x32_bf16(bfr[ni], af[mi], acc[mi][ni], 0, 0, 0);
    }
    const int rq4 = hi * 4;
    const int ncol = n0 + wn * 32 + rq4;
    const size_t cbase = (size_t)(m0 + wm * 64 + fr) * N + ncol;
    const float* pb = bias ? bias + ncol : nullptr;
#pragma unroll
    for (int mi = 0; mi < 4; ++mi) {
#pragma unroll
        for (int ni = 0; ni < 2; ++ni) {
            float v0 = acc[mi][ni][0], v1 = acc[mi][ni][1];
            float v2 = acc[mi][ni][2], v3 = acc[mi][ni][3];
            if (pb) {
                float4 b4 = *(const float4*)(pb + ni * 16);
                v0 += b4.x; v1 += b4.y; v2 += b4.z; v3 += b4.w;
            }
            if (EPI == 1) { v0 = gelu_f(v0); v1 = gelu_f(v1); v2 = gelu_f(v2); v3 = gelu_f(v3); }
            if (EPI == 2) {
                float4* p = (float4*)((float*)Cout + cbase + (size_t)mi * 16 * N + ni * 16);
                float4 o = *p;
                o.x += v0; o.y += v1; o.z += v2; o.w += v3;
                *p = o;
            } else {
                bf16x4v st = { (__bf16)v0, (__bf16)v1, (__bf16)v2, (__bf16)v3 };
                *(bf16x4v*)((bf16*)Cout + cbase + (size_t)mi * 16 * N + ni * 16) = st;
            }
        }
    }
}

// Fused MLP middle v3: C[M,192] = gelu(A[M,192] @ U^T + b1) @ V2^T.
// 64-row blocks, 24 chunks of 64 hidden. Double-buffered H (stride 72 elem:
// 9 granules/row, 9 % 8 == 1 -> rows decorrelate banks, <=2-way = free) with
// ONE barrier per chunk: write H[hc&1] -> barrier -> GEMM2 reads H[hc&1];
// the *next* barrier orders write-after-read, so GEMM2(hc) overlaps other
// waves' GEMM1(hc+1). U frags register-prefetched at distance 1; V2 frags
// issued at iter top (first use after GEMM1 -> latency hidden). 42 KB LDS
// -> 3 blocks/CU; launch_bounds(256,3) caps VGPR at 170.
__global__ __launch_bounds__(256, 3) void mlp_mid_k(const bf16* __restrict__ A,
                                                    const bf16* __restrict__ U,
                                                    const bf16* __restrict__ V2,
                                                    const float* __restrict__ b1,
                                                    bf16* __restrict__ Cout) {
    __shared__ __align__(16) bf16 lds_a[64 * 192];      // 24 KB
    __shared__ __align__(16) bf16 lds_h[2][64 * 72];    // 2 x 9 KB
    const int t = threadIdx.x;
    const int wave = t >> 6, lane = t & 63;
    const int wn = wave;
    const int fr = lane & 15, hi = lane >> 4;
    const int fp = fr & 7;
    const int m0 = blockIdx.x * 64;
    // stage A[64][192] (proven 24-slot XOR layout)
#pragma unroll
    for (int i = 0; i < 6; ++i) {
        int u = i * 256 + t;
        int row = u / 24, slot = u % 24;
        int gslot = slot ^ (row & 7);
        async16((char*)lds_a + u * 16, A + (size_t)(m0 + row) * 192 + gslot * 8);
    }

    const bf16* ub = U + (size_t)(wn * 16 + fr) * 192 + hi * 8;     // hidden rows
    const bf16* vb = V2 + (size_t)(wn * 48 + fr) * 1536 + hi * 8;   // out rows
    // preload U frags for chunk 0
    bf16x8 buc[6], bun[6];
#pragma unroll
    for (int kk = 0; kk < 6; ++kk)
        buc[kk] = *(const bf16x8*)(ub + kk * 32);
    __syncthreads();

    f32x4 acc2[4][3] = {};
#pragma unroll 1
    for (int hc = 0; hc < 24; ++hc) {
        // V2 frags for this chunk (used only after GEMM1)
        bf16x8 bvc[2][3];
#pragma unroll
        for (int kk2 = 0; kk2 < 2; ++kk2)
#pragma unroll
            for (int tn = 0; tn < 3; ++tn)
                bvc[kk2][tn] = *(const bf16x8*)(vb + (size_t)(tn * 16) * 1536 + hc * 64 + kk2 * 32);
        // prefetch U frags for chunk hc+1
        if (hc + 1 < 24) {
#pragma unroll
            for (int kk = 0; kk < 6; ++kk)
                bun[kk] = *(const bf16x8*)(ub + (size_t)(hc + 1) * 64 * 192 + kk * 32);
        }
        // ---- GEMM1: H[0:64][wn*16 .. wn*16+16) over K=192 ----
        f32x4 acc1[4] = {};
#pragma unroll
        for (int kk = 0; kk < 6; ++kk) {
            bf16x8 af[4];
#pragma unroll
            for (int mi = 0; mi < 4; ++mi) {
                int row = mi * 16 + fr;
                af[mi] = *(const bf16x8*)((const char*)lds_a + row * 384 + ((kk * 4 + hi) ^ fp) * 16);
            }
#pragma unroll
            for (int mi = 0; mi < 4; ++mi)
                acc1[mi] = __builtin_amdgcn_mfma_f32_16x16x32_bf16(buc[kk], af[mi], acc1[mi], 0, 0, 0);
        }
        // ---- gelu + bias -> H[hc&1], rows m, cols wn*16+hi*4+j ----
        {
            bf16* hbuf = lds_h[hc & 1];
            float4 b4 = *(const float4*)(b1 + hc * 64 + wn * 16 + hi * 4);
#pragma unroll
            for (int mi = 0; mi < 4; ++mi) {
                int mrow = mi * 16 + fr;
                float v0 = gelu_f(acc1[mi][0] + b4.x);
                float v1 = gelu_f(acc1[mi][1] + b4.y);
                float v2 = gelu_f(acc1[mi][2] + b4.z);
                float v3 = gelu_f(acc1[mi][3] + b4.w);
                bf16x4v st = { (__bf16)v0, (__bf16)v1, (__bf16)v2, (__bf16)v3 };
                *(bf16x4v*)(hbuf + mrow * 72 + wn * 16 + hi * 4) = st;
            }
        }
        __syncthreads();
        // ---- GEMM2: C[0:64][wn*48 .. +48) += H[0:64][0:64] @ V2c^T ----
        {
            const bf16* hbuf = lds_h[hc & 1];
#pragma unroll
            for (int kk2 = 0; kk2 < 2; ++kk2) {
                bf16x8 af2[4];
#pragma unroll
                for (int mi = 0; mi < 4; ++mi) {
                    int mrow = mi * 16 + fr;
                    af2[mi] = *(const bf16x8*)(hbuf + mrow * 72 + kk2 * 32 + hi * 8);
                }
#pragma unroll
                for (int mi = 0; mi < 4; ++mi)
#pragma unroll
                    for (int tn = 0; tn < 3; ++tn)
                        acc2[mi][tn] = __builtin_amdgcn_mfma_f32_16x16x32_bf16(bvc[kk2][tn], af2[mi], acc2[mi][tn], 0, 0, 0);
            }
        }
        // rotate U prefetch
#pragma unroll
        for (int kk = 0; kk < 6; ++kk) buc[kk] = bun[kk];
    }
    // ---- epilogue ----
    const size_t cbase = (size_t)(m0 + fr) * 192 + wn * 48 + hi * 4;
#pragma unroll
    for (int mi = 0; mi < 4; ++mi) {
#pragma unroll
        for (int tn = 0; tn < 3; ++tn) {
            bf16x4v st = { (__bf16)acc2[mi][tn][0], (__bf16)acc2[mi][tn][1],
                           (__bf16)acc2[mi][tn][2], (__bf16)acc2[mi][tn][3] };
            *(bf16x4v*)(Cout + cbase + (size_t)mi * 16 * 192 + tn * 16) = st;
        }
    }
}

extern "C" void kernel_launch(void* const* d_in, const int* in_sizes, int n_in,
                              void* d_out, int out_size, void* d_ws, size_t ws_size,
                              hipStream_t stream) {
    const float* x      = (const float*)d_in[0];
    const float* n1g    = (const float*)d_in[1];
    const float* n1b    = (const float*)d_in[2];
    const float* rpbt   = (const float*)d_in[3];
    const float* qkv_v  = (const float*)d_in[4];
    const float* qkv_u  = (const float*)d_in[5];
    const float* qkv_b  = (const float*)d_in[6];
    const float* proj_v = (const float*)d_in[7];
    const float* proj_u = (const float*)d_in[8];
    const float* proj_b = (const float*)d_in[9];
    const float* n2g    = (const float*)d_in[10];
    const float* n2b    = (const float*)d_in[11];
    const float* fc1_v  = (const float*)d_in[12];
    const float* fc1_u  = (const float*)d_in[13];
    const float* fc1_b  = (const float*)d_in[14];
    const float* fc2_v  = (const float*)d_in[15];
    const float* fc2_u  = (const float*)d_in[16];
    const float* fc2_b  = (const float*)d_in[17];

    char* ws = (char*)d_ws;
    bf16* wb = (bf16*)ws;
    bf16* w_qkv_v  = wb;
    bf16* w_qkv_u  = wb + 73728;
    bf16* w_proj_v = wb + 294912;
    bf16* w_proj_u = wb + 368640;
    bf16* w_fc1_v  = wb + 442368;
    bf16* w_fc1_u  = wb + 516096;
    bf16* w_fc2_v  = wb + 811008;
    bf16* w_fc2_u  = wb + 1105920;
    bf16* w_proj_m = wb + 1179648;             // 384x384 merged proj
    float* biasf   = (float*)(ws + 3145728);   // 768 KB
    size_t off = (size_t)4 << 20;
    bf16* R1 = (bf16*)(ws + off); off += (size_t)MROWS * 1536 * 2;   // qkv / proj-out / mlp-out
    bf16* R2 = (bf16*)(ws + off); off += (size_t)MROWS * 384 * 2;    // ywin / o / z
    bf16* R3 = (bf16*)(ws + off);                                    // rank-192 temps
    float* out = (float*)d_out;

    Cvt8 c;
    c.s[0] = qkv_v;  c.d[0] = w_qkv_v;  c.n[0] = 73728;
    c.s[1] = qkv_u;  c.d[1] = w_qkv_u;  c.n[1] = 221184;
    c.s[2] = proj_v; c.d[2] = w_proj_v; c.n[2] = 73728;
    c.s[3] = proj_u; c.d[3] = w_proj_u; c.n[3] = 73728;
    c.s[4] = fc1_v;  c.d[4] = w_fc1_v;  c.n[4] = 73728;
    c.s[5] = fc1_u;  c.d[5] = w_fc1_u;  c.n[5] = 294912;
    c.s[6] = fc2_v;  c.d[6] = w_fc2_v;  c.n[6] = 294912;
    c.s[7] = fc2_u;  c.d[7] = w_fc2_u;  c.n[7] = 73728;
    cvt8_k<<<dim3(288, 8), 256, 0, stream>>>(c);
    bias_pre_k<<<48, 256, 0, stream>>>(rpbt, biasf);
    wmerge_k<<<384, 384, 0, stream>>>(proj_u, proj_v, w_proj_m);

    ln1_window_k<<<MROWS / 4, 256, 0, stream>>>(x, n1g, n1b, R2);
    gemm_bt<384, 192, 2, 0><<<dim3(3, 784), 256, 0, stream>>>(R2, w_qkv_v, nullptr, R3);
    gemm_bt<192, 1152, 4, 0><<<dim3(9, 784), 512, 0, stream>>>(R3, w_qkv_u, qkv_b, R1);
    attn_mfma_k<<<dim3(2048, 3), 256, 0, stream>>>(R1, biasf, R2);
    gemm_bt<384, 384, 4, 0><<<dim3(3, 784), 512, 0, stream>>>(R2, w_proj_m, proj_b, R1);
    resid_ln2_k<<<MROWS / 4, 256, 0, stream>>>(x, R1, n2g, n2b, out, R2);
    gemm_bt<384, 192, 2, 0><<<dim3(3, 784), 256, 0, stream>>>(R2, w_fc1_v, nullptr, R3);
    mlp_mid_k<<<1568, 256, 0, stream>>>(R3, w_fc1_u, w_fc2_v, fc1_b, R1);
    gemm_bt<192, 384, 4, 2><<<dim3(3, 784), 512, 0, stream>>>(R1, w_fc2_u, fc2_b, out);
}

// Round 17
// 721.671 us; speedup vs baseline: 1.2934x; 1.1226x over previous
//
#include <hip/hip_runtime.h>
#include <hip/hip_bf16.h>

using bf16 = __hip_bfloat16;
typedef __bf16 bf16x8 __attribute__((ext_vector_type(8)));
typedef __bf16 bf16x4v __attribute__((ext_vector_type(4)));
typedef float f32x4 __attribute__((ext_vector_type(4)));

#define MROWS 100352   // 2048 windows * 49 tokens = 32*3136

__device__ __forceinline__ void async16(void* l, const void* g) {
    void* gg = const_cast<void*>(g);
    __builtin_amdgcn_global_load_lds((__attribute__((address_space(1))) void*)gg,
                                     (__attribute__((address_space(3))) void*)l, 16, 0, 0);
}

// tanh-gelu via sigmoid identity: 0.5x(1+tanh(u)) == x*sigmoid(2u)
__device__ __forceinline__ float gelu_f(float x) {
    float u = x * fmaf(0.044715f * x, x, 1.0f);
    float e = __expf(-1.5957691216057308f * u);
    return x * __builtin_amdgcn_rcpf(1.0f + e);
}

struct Cvt8 { const float* s[8]; bf16* d[8]; int n[8]; };

__global__ __launch_bounds__(256) void cvt8_k(Cvt8 c) {
    int seg = blockIdx.y;
    int i4 = (blockIdx.x * 256 + threadIdx.x) * 4;
    if (i4 < c.n[seg]) {
        float4 v = *(const float4*)(c.s[seg] + i4);
        bf16* d = c.d[seg] + i4;
        d[0] = __float2bfloat16(v.x);
        d[1] = __float2bfloat16(v.y);
        d[2] = __float2bfloat16(v.z);
        d[3] = __float2bfloat16(v.w);
    }
}

// merged proj weight: Wm[384][384] = proj_u(384x192) @ proj_v(192x384), bf16.
__global__ __launch_bounds__(384) void wmerge_k(const float* __restrict__ u,
                                                const float* __restrict__ v,
                                                bf16* __restrict__ wm) {
    int o = blockIdx.x, i = threadIdx.x;
    const float* ur = u + o * 192;
    float acc = 0.f;
    for (int r = 0; r < 192; ++r) acc = fmaf(ur[r], v[r * 384 + i], acc);
    wm[o * 384 + i] = __float2bfloat16(acc);
}

// Reorder fc1_u[1536][192] (f32) into fragment-linear bf16:
// group g = (hc*6+kk)*256 + w*64 + lane; dst[g*8+e] = U[hc*64+w*16+(lane&15)][kk*32+(lane>>4)*8+e]
// -> mlp_mid's GEMM1 B-frag load becomes base + lane*16 (fully coalesced).
__global__ __launch_bounds__(256) void u_reord_k(const float* __restrict__ U,
                                                 bf16* __restrict__ Ur) {
    int g = blockIdx.x * 256 + threadIdx.x;           // 36864 groups
    int lane = g & 63, w = (g >> 6) & 3, q = g >> 8;  // q = hc*6+kk
    int kk = q % 6, hc = q / 6;
    int row = hc * 64 + w * 16 + (lane & 15);
    int col = kk * 32 + (lane >> 4) * 8;
    const float* src = U + (size_t)row * 192 + col;
    bf16* d = Ur + (size_t)g * 8;
#pragma unroll
    for (int e = 0; e < 8; ++e) d[e] = __float2bfloat16(src[e]);
}

// Reorder fc2_v[192][1536] (f32) similarly:
// g = (((hc*2+kk2)*4+w)*3+tn)*64 + lane; dst[g*8+e] = V2[w*48+tn*16+(lane&15)][hc*64+kk2*32+(lane>>4)*8+e]
__global__ __launch_bounds__(256) void v_reord_k(const float* __restrict__ V2,
                                                 bf16* __restrict__ Vr) {
    int g = blockIdx.x * 256 + threadIdx.x;           // 36864 groups
    int lane = g & 63;
    int r = g >> 6;
    int tn = r % 3; r /= 3;
    int w = r & 3; r >>= 2;
    int kk2 = r & 1;
    int hc = r >> 1;
    int row = w * 48 + tn * 16 + (lane & 15);
    int col = hc * 64 + kk2 * 32 + (lane >> 4) * 8;
    const float* src = V2 + (size_t)row * 1536 + col;
    bf16* d = Vr + (size_t)g * 8;
#pragma unroll
    for (int e = 0; e < 8; ++e) d[e] = __float2bfloat16(src[e]);
}

// Precompute attn bias (rpb + shift-mask) in C-fragment layout.
__global__ __launch_bounds__(256) void bias_pre_k(const float* __restrict__ rpbt,
                                                  float* __restrict__ biasf) {
    int wt = blockIdx.x / 12, h = blockIdx.x % 12;
    int t = threadIdx.x;
    int lane = t >> 2, tb = t & 3;
    int hi = lane >> 4, lo = lane & 15;
    int m = tb * 16 + lo;
    bool bH = (wt & 2) != 0, bW = (wt & 1) != 0;
    float* outb = biasf + (size_t)blockIdx.x * 4096;
    int mm = m < 49 ? m : 0;
    int i2 = mm / 7, j2 = mm % 7;
    int rm = (bH ? (i2 < 4 ? 1 : 2) : 0) * 3 + (bW ? (j2 < 4 ? 1 : 2) : 0);
#pragma unroll
    for (int ta = 0; ta < 4; ++ta) {
#pragma unroll
        for (int j = 0; j < 4; ++j) {
            int n = ta * 16 + hi * 4 + j;
            float v;
            if (n < 49 && m < 49) {
                int i1 = n / 7, j1 = n % 7;
                int rn = (bH ? (i1 < 4 ? 1 : 2) : 0) * 3 + (bW ? (j1 < 4 ? 1 : 2) : 0);
                v = rpbt[((i1 - i2 + 6) * 13 + (j1 - j2 + 6)) * 12 + h];
                if (rn != rm) v -= 100.0f;
            } else {
                v = -1e30f;
            }
            outb[(ta * 4 + j) * 256 + t] = v;
        }
    }
}

// LN1 + cyclic shift(-3,-3) + window partition. One wave per output row.
__global__ __launch_bounds__(256) void ln1_window_k(const float* __restrict__ x,
                                                    const float* __restrict__ g,
                                                    const float* __restrict__ bta,
                                                    bf16* __restrict__ ywin) {
    int wrow = blockIdx.x * 4 + (threadIdx.x >> 6);
    int lane = threadIdx.x & 63;
    int tok = wrow % 49, win = wrow / 49;
    int i = tok / 7, j = tok % 7;
    int wwi = win & 7, whi = (win >> 3) & 7, bi = win >> 6;
    int hs = (whi * 7 + i + 3) % 56;
    int ws_ = (wwi * 7 + j + 3) % 56;
    const float* xr = x + ((size_t)bi * 3136 + (size_t)hs * 56 + ws_) * 384;
    float v[6]; float s = 0.f, s2 = 0.f;
#pragma unroll
    for (int u = 0; u < 6; ++u) { float t = xr[lane + 64 * u]; v[u] = t; s += t; s2 += t * t; }
#pragma unroll
    for (int d = 1; d < 64; d <<= 1) { s += __shfl_xor(s, d); s2 += __shfl_xor(s2, d); }
    float mean = s * (1.0f / 384.0f);
    float var = s2 * (1.0f / 384.0f) - mean * mean;
    float rstd = rsqrtf(var + 1e-5f);
    bf16* yr = ywin + (size_t)wrow * 384;
#pragma unroll
    for (int u = 0; u < 6; ++u) {
        int c = lane + 64 * u;
        yr[c] = __float2bfloat16((v[u] - mean) * rstd * g[c] + bta[c]);
    }
}

// residual add (window-reverse + roll(+3,+3)) + LN2. x2 -> d_out (fp32), z -> bf16
__global__ __launch_bounds__(256) void resid_ln2_k(const float* __restrict__ x,
                                                   const bf16* __restrict__ proj,
                                                   const float* __restrict__ g,
                                                   const float* __restrict__ bta,
                                                   float* __restrict__ x2,
                                                   bf16* __restrict__ z) {
    int row = blockIdx.x * 4 + (threadIdx.x >> 6);
    int lane = threadIdx.x & 63;
    int bi = row / 3136; int hw = row % 3136;
    int h = hw / 56, w = hw % 56;
    int h2 = (h + 53) % 56, w2 = (w + 53) % 56;
    int prow = ((bi * 8 + h2 / 7) * 8 + w2 / 7) * 49 + (h2 % 7) * 7 + (w2 % 7);
    const float* xr = x + (size_t)row * 384;
    const bf16* pr = proj + (size_t)prow * 384;
    float* x2r = x2 + (size_t)row * 384;
    float v[6]; float s = 0.f, s2 = 0.f;
#pragma unroll
    for (int u = 0; u < 6; ++u) {
        int c = lane + 64 * u;
        float t = xr[c] + __bfloat162float(pr[c]);
        v[u] = t; s += t; s2 += t * t;
        x2r[c] = t;
    }
#pragma unroll
    for (int d = 1; d < 64; d <<= 1) { s += __shfl_xor(s, d); s2 += __shfl_xor(s2, d); }
    float mean = s * (1.0f / 384.0f);
    float var = s2 * (1.0f / 384.0f) - mean * mean;
    float rstd = rsqrtf(var + 1e-5f);
    bf16* zr = z + (size_t)row * 384;
#pragma unroll
    for (int u = 0; u < 6; ++u) {
        int c = lane + 64 * u;
        zr[c] = __float2bfloat16((v[u] - mean) * rstd * g[c] + bta[c]);
    }
}

// MFMA windowed attention (unchanged, round-10-verified).
__global__ __launch_bounds__(256) void attn_mfma_k(const bf16* __restrict__ qkv,
                                                   const float* __restrict__ biasf,
                                                   bf16* __restrict__ o) {
    __shared__ __align__(16) __bf16 vt_s[4][32 * 72];
    __shared__ __align__(16) __bf16 p_s[4][32 * 72];
    const int win = blockIdx.x;
    const int r = blockIdx.y;
    const int wave = threadIdx.x >> 6, lane = threadIdx.x & 63;
    const int lo = lane & 15, hi = lane >> 4;
    const int whi = (win >> 3) & 7, wwi = win & 7;
    const int wt = ((whi == 7) ? 2 : 0) + ((wwi == 7) ? 1 : 0);
    __bf16* vt_w = vt_s[wave];
    __bf16* p_w = p_s[wave];
    const int h = r * 4 + wave;
    const bf16* qbase = qkv + (size_t)win * 49 * 1152 + h * 32;
    const float* btile = biasf + (size_t)(wt * 12 + h) * 4096;
    bf16x8 zf = {};

    {
        int m = lane;
        bf16x8 vrow[4];
#pragma unroll
        for (int d8 = 0; d8 < 4; ++d8)
            vrow[d8] = (m < 49) ? *(const bf16x8*)(qbase + (size_t)m * 1152 + 768 + d8 * 8) : zf;
#pragma unroll
        for (int d8 = 0; d8 < 4; ++d8)
#pragma unroll
            for (int e = 0; e < 8; ++e)
                vt_w[(d8 * 8 + e) * 72 + m] = vrow[d8][e];
    }
    bf16x8 aq[4], bk[4];
    const int kq = hi * 8;
#pragma unroll
    for (int ta = 0; ta < 4; ++ta) {
        int n = ta * 16 + lo;
        aq[ta] = (n < 49) ? *(const bf16x8*)(qbase + (size_t)n * 1152 + kq) : zf;
        bk[ta] = (n < 49) ? *(const bf16x8*)(qbase + (size_t)n * 1152 + 384 + kq) : zf;
    }
    f32x4 acc[4][4] = {};
#pragma unroll
    for (int ta = 0; ta < 4; ++ta)
#pragma unroll
        for (int tb = 0; tb < 4; ++tb)
            acc[ta][tb] = __builtin_amdgcn_mfma_f32_16x16x32_bf16(aq[ta], bk[tb], acc[ta][tb], 0, 0, 0);
#pragma unroll
    for (int ta = 0; ta < 4; ++ta) {
#pragma unroll
        for (int j = 0; j < 4; ++j) {
            float4 b4 = *(const float4*)(btile + (ta * 4 + j) * 256 + lane * 4);
            acc[ta][0][j] = fmaf(acc[ta][0][j], 0.17677669529663687f, b4.x);
            acc[ta][1][j] = fmaf(acc[ta][1][j], 0.17677669529663687f, b4.y);
            acc[ta][2][j] = fmaf(acc[ta][2][j], 0.17677669529663687f, b4.z);
            acc[ta][3][j] = fmaf(acc[ta][3][j], 0.17677669529663687f, b4.w);
        }
    }
    bf16x8 vb[2][2];
#pragma unroll
    for (int kb = 0; kb < 2; ++kb)
#pragma unroll
        for (int tb = 0; tb < 2; ++tb)
            vb[kb][tb] = *(const bf16x8*)(vt_w + (tb * 16 + lo) * 72 + kb * 32 + hi * 8);

    f32x4 oacc[4][2] = {};
#pragma unroll
    for (int half = 0; half < 2; ++half) {
#pragma unroll
        for (int tq = 0; tq < 2; ++tq) {
            int ta = half * 2 + tq;
#pragma unroll
            for (int j = 0; j < 4; ++j) {
                float mx = fmaxf(fmaxf(acc[ta][0][j], acc[ta][1][j]),
                                 fmaxf(acc[ta][2][j], acc[ta][3][j]));
                mx = fmaxf(mx, __shfl_xor(mx, 1));
                mx = fmaxf(mx, __shfl_xor(mx, 2));
                mx = fmaxf(mx, __shfl_xor(mx, 4));
                mx = fmaxf(mx, __shfl_xor(mx, 8));
                float e0 = __expf(acc[ta][0][j] - mx);
                float e1 = __expf(acc[ta][1][j] - mx);
                float e2 = __expf(acc[ta][2][j] - mx);
                float e3 = __expf(acc[ta][3][j] - mx);
                float sm = e0 + e1 + e2 + e3;
                sm += __shfl_xor(sm, 1);
                sm += __shfl_xor(sm, 2);
                sm += __shfl_xor(sm, 4);
                sm += __shfl_xor(sm, 8);
                float inv = __builtin_amdgcn_rcpf(sm);
                int nl = tq * 16 + hi * 4 + j;
                p_w[nl * 72 + lo]      = (__bf16)(e0 * inv);
                p_w[nl * 72 + 16 + lo] = (__bf16)(e1 * inv);
                p_w[nl * 72 + 32 + lo] = (__bf16)(e2 * inv);
                p_w[nl * 72 + 48 + lo] = (__bf16)(e3 * inv);
            }
        }
#pragma unroll
        for (int kb = 0; kb < 2; ++kb) {
#pragma unroll
            for (int tq = 0; tq < 2; ++tq) {
                bf16x8 pa = *(const bf16x8*)(p_w + (tq * 16 + lo) * 72 + kb * 32 + hi * 8);
#pragma unroll
                for (int tb = 0; tb < 2; ++tb)
                    oacc[half * 2 + tq][tb] =
                        __builtin_amdgcn_mfma_f32_16x16x32_bf16(pa, vb[kb][tb], oacc[half * 2 + tq][tb], 0, 0, 0);
            }
        }
    }
    bf16* obase = o + (size_t)win * 49 * 384 + h * 32;
#pragma unroll
    for (int ta = 0; ta < 4; ++ta) {
#pragma unroll
        for (int j = 0; j < 4; ++j) {
            int n = ta * 16 + hi * 4 + j;
            if (n < 49) {
#pragma unroll
                for (int tb = 0; tb < 2; ++tb)
                    obase[(size_t)n * 384 + tb * 16 + lo] = __float2bfloat16(oacc[ta][tb][j]);
            }
        }
    }
}

// R12-proven GEMM template. WN=2: 256thr 128x64; WN=4: 512thr 128x128.
template <int K, int N, int WN, int EPI>
__global__ __launch_bounds__(WN * 128, 8 - WN) void gemm_bt(const bf16* __restrict__ A,
                                                            const bf16* __restrict__ W,
                                                            const float* __restrict__ bias,
                                                            void* __restrict__ Cout) {
    constexpr int T = WN * 128;
    constexpr int BN = WN * 32;
    __shared__ __align__(16) bf16 lds_a[128 * 64];
    __shared__ __align__(16) bf16 lds_b[BN * 64];
    const int t = threadIdx.x;
    const int wave = t >> 6, lane = t & 63;
    const int gdx = gridDim.x;
    int flat = blockIdx.y * gdx + blockIdx.x;
    int q = (gdx * gridDim.y) >> 3;
    int work = (flat & 7) * q + (flat >> 3);
    const int n0 = (work % gdx) * BN, m0 = (work / gdx) * 128;
    const int wm = wave / WN, wn = wave % WN;
    const int fr = lane & 15, hi = lane >> 4;
    const int srow = t >> 3;
    const int gslot = (t & 7) ^ (srow & 7);
    const bf16* abase = A + (size_t)(m0 + srow) * K + gslot * 8;
    const bf16* bbase = W + (size_t)(n0 + srow) * K + gslot * 8;
    char* la = (char*)lds_a + t * 16;
    char* lb = (char*)lds_b + t * 16;
    const int fp = fr & 7;
    const char* ra0 = (const char*)lds_a + (wm * 64 + fr) * 128 + (hi ^ fp) * 16;
    const char* ra1 = (const char*)lds_a + (wm * 64 + fr) * 128 + ((4 + hi) ^ fp) * 16;
    const char* rb0 = (const char*)lds_b + (wn * 32 + fr) * 128 + (hi ^ fp) * 16;
    const char* rb1 = (const char*)lds_b + (wn * 32 + fr) * 128 + ((4 + hi) ^ fp) * 16;
    f32x4 acc[4][2] = {};
#pragma unroll
    for (int kt = 0; kt < K; kt += 64) {
        if (kt > 0) __syncthreads();
#pragma unroll
        for (int i = 0; i < 1024 / T; ++i)
            async16(la + i * T * 16, abase + (size_t)i * (T >> 3) * K + kt);
#pragma unroll
        for (int i = 0; i < BN * 8 / T; ++i)
            async16(lb + i * T * 16, bbase + (size_t)i * (T >> 3) * K + kt);
        __syncthreads();
        bf16x8 af[4], bfr[2];
#pragma unroll
        for (int mi = 0; mi < 4; ++mi) af[mi] = *(const bf16x8*)(ra0 + mi * 2048);
#pragma unroll
        for (int ni = 0; ni < 2; ++ni) bfr[ni] = *(const bf16x8*)(rb0 + ni * 2048);
#pragma unroll
        for (int mi = 0; mi < 4; ++mi)
#pragma unroll
            for (int ni = 0; ni < 2; ++ni)
                acc[mi][ni] = __builtin_amdgcn_mfma_f32_16x16x32_bf16(bfr[ni], af[mi], acc[mi][ni], 0, 0, 0);
#pragma unroll
        for (int mi = 0; mi < 4; ++mi) af[mi] = *(const bf16x8*)(ra1 + mi * 2048);
#pragma unroll
        for (int ni = 0; ni < 2; ++ni) bfr[ni] = *(const bf16x8*)(rb1 + ni * 2048);
#pragma unroll
        for (int mi = 0; mi < 4; ++mi)
#pragma unroll
            for (int ni = 0; ni < 2; ++ni)
                acc[mi][ni] = __builtin_amdgcn_mfma_f32_16x16x32_bf16(bfr[ni], af[mi], acc[mi][ni], 0, 0, 0);
    }
    const int rq4 = hi * 4;
    const int ncol = n0 + wn * 32 + rq4;
    const size_t cbase = (size_t)(m0 + wm * 64 + fr) * N + ncol;
    const float* pb = bias ? bias + ncol : nullptr;
#pragma unroll
    for (int mi = 0; mi < 4; ++mi) {
#pragma unroll
        for (int ni = 0; ni < 2; ++ni) {
            float v0 = acc[mi][ni][0], v1 = acc[mi][ni][1];
            float v2 = acc[mi][ni][2], v3 = acc[mi][ni][3];
            if (pb) {
                float4 b4 = *(const float4*)(pb + ni * 16);
                v0 += b4.x; v1 += b4.y; v2 += b4.z; v3 += b4.w;
            }
            if (EPI == 1) { v0 = gelu_f(v0); v1 = gelu_f(v1); v2 = gelu_f(v2); v3 = gelu_f(v3); }
            if (EPI == 2) {
                float4* p = (float4*)((float*)Cout + cbase + (size_t)mi * 16 * N + ni * 16);
                float4 o = *p;
                o.x += v0; o.y += v1; o.z += v2; o.w += v3;
                *p = o;
            } else {
                bf16x4v st = { (__bf16)v0, (__bf16)v1, (__bf16)v2, (__bf16)v3 };
                *(bf16x4v*)((bf16*)Cout + cbase + (size_t)mi * 16 * N + ni * 16) = st;
            }
        }
    }
}

// Fused MLP middle v4: same structure as v3, but U/V2 come from the
// fragment-linear reordered copies -> every weight load is base + lane*16
// (one coalesced 1 KB wave transaction, vs 64 scattered 16B lines before:
// THAT was the invariant bottleneck across v1-v3).
__global__ __launch_bounds__(256, 3) void mlp_mid_k(const bf16* __restrict__ A,
                                                    const bf16* __restrict__ Ur,
                                                    const bf16* __restrict__ Vr,
                                                    const float* __restrict__ b1,
                                                    bf16* __restrict__ Cout) {
    __shared__ __align__(16) bf16 lds_a[64 * 192];      // 24 KB
    __shared__ __align__(16) bf16 lds_h[2][64 * 72];    // 2 x 9 KB
    const int t = threadIdx.x;
    const int wave = t >> 6, lane = t & 63;
    const int wn = wave;
    const int fr = lane & 15, hi = lane >> 4;
    const int fp = fr & 7;
    const int m0 = blockIdx.x * 64;
#pragma unroll
    for (int i = 0; i < 6; ++i) {
        int u = i * 256 + t;
        int row = u / 24, slot = u % 24;
        int gslot = slot ^ (row & 7);
        async16((char*)lds_a + u * 16, A + (size_t)(m0 + row) * 192 + gslot * 8);
    }

    // fragment-linear weight bases (coalesced: consecutive lanes -> consecutive 16B)
    const bf16* ubase = Ur + ((size_t)wn * 64 + lane) * 8;      // + (hc*6+kk)*2048
    const bf16* vbase = Vr + ((size_t)wn * 3 * 64 + lane) * 8;  // + (hc*2+kk2)*6144 + tn*512
    bf16x8 buc[6], bun[6];
#pragma unroll
    for (int kk = 0; kk < 6; ++kk)
        buc[kk] = *(const bf16x8*)(ubase + (size_t)kk * 2048);
    __syncthreads();

    f32x4 acc2[4][3] = {};
#pragma unroll 1
    for (int hc = 0; hc < 24; ++hc) {
        bf16x8 bvc[2][3];
#pragma unroll
        for (int kk2 = 0; kk2 < 2; ++kk2)
#pragma unroll
            for (int tn = 0; tn < 3; ++tn)
                bvc[kk2][tn] = *(const bf16x8*)(vbase + (size_t)(hc * 2 + kk2) * 6144 + tn * 512);
        if (hc + 1 < 24) {
#pragma unroll
            for (int kk = 0; kk < 6; ++kk)
                bun[kk] = *(const bf16x8*)(ubase + (size_t)((hc + 1) * 6 + kk) * 2048);
        }
        // ---- GEMM1: H[0:64][wn*16 .. +16) over K=192 ----
        f32x4 acc1[4] = {};
#pragma unroll
        for (int kk = 0; kk < 6; ++kk) {
            bf16x8 af[4];
#pragma unroll
            for (int mi = 0; mi < 4; ++mi) {
                int row = mi * 16 + fr;
                af[mi] = *(const bf16x8*)((const char*)lds_a + row * 384 + ((kk * 4 + hi) ^ fp) * 16);
            }
#pragma unroll
            for (int mi = 0; mi < 4; ++mi)
                acc1[mi] = __builtin_amdgcn_mfma_f32_16x16x32_bf16(buc[kk], af[mi], acc1[mi], 0, 0, 0);
        }
        // ---- gelu + bias -> H[hc&1] ----
        {
            bf16* hbuf = lds_h[hc & 1];
            float4 b4 = *(const float4*)(b1 + hc * 64 + wn * 16 + hi * 4);
#pragma unroll
            for (int mi = 0; mi < 4; ++mi) {
                int mrow = mi * 16 + fr;
                float v0 = gelu_f(acc1[mi][0] + b4.x);
                float v1 = gelu_f(acc1[mi][1] + b4.y);
                float v2 = gelu_f(acc1[mi][2] + b4.z);
                float v3 = gelu_f(acc1[mi][3] + b4.w);
                bf16x4v st = { (__bf16)v0, (__bf16)v1, (__bf16)v2, (__bf16)v3 };
                *(bf16x4v*)(hbuf + mrow * 72 + wn * 16 + hi * 4) = st;
            }
        }
        __syncthreads();
        // ---- GEMM2: C[0:64][wn*48 .. +48) += H @ V2c^T ----
        {
            const bf16* hbuf = lds_h[hc & 1];
#pragma unroll
            for (int kk2 = 0; kk2 < 2; ++kk2) {
                bf16x8 af2[4];
#pragma unroll
                for (int mi = 0; mi < 4; ++mi) {
                    int mrow = mi * 16 + fr;
                    af2[mi] = *(const bf16x8*)(hbuf + mrow * 72 + kk2 * 32 + hi * 8);
                }
#pragma unroll
                for (int mi = 0; mi < 4; ++mi)
#pragma unroll
                    for (int tn = 0; tn < 3; ++tn)
                        acc2[mi][tn] = __builtin_amdgcn_mfma_f32_16x16x32_bf16(bvc[kk2][tn], af2[mi], acc2[mi][tn], 0, 0, 0);
            }
        }
#pragma unroll
        for (int kk = 0; kk < 6; ++kk) buc[kk] = bun[kk];
    }
    const size_t cbase = (size_t)(m0 + fr) * 192 + wn * 48 + hi * 4;
#pragma unroll
    for (int mi = 0; mi < 4; ++mi) {
#pragma unroll
        for (int tn = 0; tn < 3; ++tn) {
            bf16x4v st = { (__bf16)acc2[mi][tn][0], (__bf16)acc2[mi][tn][1],
                           (__bf16)acc2[mi][tn][2], (__bf16)acc2[mi][tn][3] };
            *(bf16x4v*)(Cout + cbase + (size_t)mi * 16 * 192 + tn * 16) = st;
        }
    }
}

extern "C" void kernel_launch(void* const* d_in, const int* in_sizes, int n_in,
                              void* d_out, int out_size, void* d_ws, size_t ws_size,
                              hipStream_t stream) {
    const float* x      = (const float*)d_in[0];
    const float* n1g    = (const float*)d_in[1];
    const float* n1b    = (const float*)d_in[2];
    const float* rpbt   = (const float*)d_in[3];
    const float* qkv_v  = (const float*)d_in[4];
    const float* qkv_u  = (const float*)d_in[5];
    const float* qkv_b  = (const float*)d_in[6];
    const float* proj_v = (const float*)d_in[7];
    const float* proj_u = (const float*)d_in[8];
    const float* proj_b = (const float*)d_in[9];
    const float* n2g    = (const float*)d_in[10];
    const float* n2b    = (const float*)d_in[11];
    const float* fc1_v  = (const float*)d_in[12];
    const float* fc1_u  = (const float*)d_in[13];
    const float* fc1_b  = (const float*)d_in[14];
    const float* fc2_v  = (const float*)d_in[15];
    const float* fc2_u  = (const float*)d_in[16];
    const float* fc2_b  = (const float*)d_in[17];

    char* ws = (char*)d_ws;
    bf16* wb = (bf16*)ws;
    bf16* w_qkv_v  = wb;
    bf16* w_qkv_u  = wb + 73728;
    bf16* w_proj_v = wb + 294912;
    bf16* w_proj_u = wb + 368640;
    bf16* w_fc1_v  = wb + 442368;
    bf16* w_fc1_u  = wb + 516096;
    bf16* w_fc2_v  = wb + 811008;
    bf16* w_fc2_u  = wb + 1105920;
    bf16* w_proj_m = wb + 1179648;               // 384x384 merged proj
    float* biasf   = (float*)(ws + 3145728);     // 768 KB
    bf16* w_u_r    = (bf16*)(ws + 4194304);      // 576 KB fragment-linear fc1_u
    bf16* w_v_r    = (bf16*)(ws + 4784128);      // 576 KB fragment-linear fc2_v
    size_t off = (size_t)6 << 20;
    bf16* R1 = (bf16*)(ws + off); off += (size_t)MROWS * 1536 * 2;   // qkv / proj-out / mlp-out
    bf16* R2 = (bf16*)(ws + off); off += (size_t)MROWS * 384 * 2;    // ywin / o / z
    bf16* R3 = (bf16*)(ws + off);                                    // rank-192 temps
    float* out = (float*)d_out;

    Cvt8 c;
    c.s[0] = qkv_v;  c.d[0] = w_qkv_v;  c.n[0] = 73728;
    c.s[1] = qkv_u;  c.d[1] = w_qkv_u;  c.n[1] = 221184;
    c.s[2] = proj_v; c.d[2] = w_proj_v; c.n[2] = 73728;
    c.s[3] = proj_u; c.d[3] = w_proj_u; c.n[3] = 73728;
    c.s[4] = fc1_v;  c.d[4] = w_fc1_v;  c.n[4] = 73728;
    c.s[5] = fc1_u;  c.d[5] = w_fc1_u;  c.n[5] = 294912;
    c.s[6] = fc2_v;  c.d[6] = w_fc2_v;  c.n[6] = 294912;
    c.s[7] = fc2_u;  c.d[7] = w_fc2_u;  c.n[7] = 73728;
    cvt8_k<<<dim3(288, 8), 256, 0, stream>>>(c);
    bias_pre_k<<<48, 256, 0, stream>>>(rpbt, biasf);
    wmerge_k<<<384, 384, 0, stream>>>(proj_u, proj_v, w_proj_m);
    u_reord_k<<<144, 256, 0, stream>>>(fc1_u, w_u_r);
    v_reord_k<<<144, 256, 0, stream>>>(fc2_v, w_v_r);

    ln1_window_k<<<MROWS / 4, 256, 0, stream>>>(x, n1g, n1b, R2);
    gemm_bt<384, 192, 2, 0><<<dim3(3, 784), 256, 0, stream>>>(R2, w_qkv_v, nullptr, R3);
    gemm_bt<192, 1152, 4, 0><<<dim3(9, 784), 512, 0, stream>>>(R3, w_qkv_u, qkv_b, R1);
    attn_mfma_k<<<dim3(2048, 3), 256, 0, stream>>>(R1, biasf, R2);
    gemm_bt<384, 384, 4, 0><<<dim3(3, 784), 512, 0, stream>>>(R2, w_proj_m, proj_b, R1);
    resid_ln2_k<<<MROWS / 4, 256, 0, stream>>>(x, R1, n2g, n2b, out, R2);
    gemm_bt<384, 192, 2, 0><<<dim3(3, 784), 256, 0, stream>>>(R2, w_fc1_v, nullptr, R3);
    mlp_mid_k<<<1568, 256, 0, stream>>>(R3, w_u_r, w_v_r, fc1_b, R1);
    gemm_bt<192, 384, 4, 2><<<dim3(3, 784), 512, 0, stream>>>(R1, w_fc2_u, fc2_b, out);
}